// Round 5
// baseline (12060.088 us; speedup 1.0000x reference)
//
#include <hip/hip_runtime.h>
#include <hip/hip_bf16.h>
#include <math.h>

// CaptionModel: 200-step GRU (B=256,H=512) + projection V=100.
// Round-5: single PERSISTENT kernel (256 blocks = 1/CU, software grid
// barrier per step). Round-4 counters showed L2 is cold at every dispatch
// boundary (FETCH_SIZE ~= full 9.4 MB weight set per step, 170 GB/s,
// MfmaUtil 2.5%) -> 47 us/step latency-bound. Persistent kernel fetches
// weights once; they stay in L2 for all 200 steps.
// Numerics (unchanged from round 4, which passed at absmax 0.0078):
// 3-way bf16 splits (rep 2^-27), zeroed f32 MFMA chains per K=32 chunk,
// f64 chunk combine + f64 gates + f64 h carry (recurrence amplifies ~2e5).
// s>=1: x==h  =>  r,z gates use precombined (w_ih+w_hh): 24 MFMAs/tile/chunk.
// s==0 via wh-only slabs + precomputed gi0 = x0 @ w_ih^T (f64 vector).

typedef __bf16 bf16_t;
typedef __bf16 bf16x8 __attribute__((ext_vector_type(8)));
typedef float f32x4 __attribute__((ext_vector_type(4)));

#define B_ 256
#define H_ 512
#define V_ 100
#define T_ 200
#define NF_ 131072              // B_*H_
#define SLAB_ 24576             // 3 splits * 16 chunks * 16 rows * 32 k
#define NBLK_ 256
#define MFMA(a,b,c) __builtin_amdgcn_mfma_f32_16x16x32_bf16((a),(b),(c),0,0,0)

__device__ __forceinline__ float ld_in(const void* p, long i, int isf32) {
    return isf32 ? ((const float*)p)[i] : (float)((const bf16_t*)p)[i];
}

__device__ __forceinline__ bf16_t split_pick(double v, int sp) {
    bf16_t a = (bf16_t)(float)v;
    if (sp == 0) return a;
    double r1 = v - (double)(float)a;
    bf16_t b = (bf16_t)(float)r1;
    if (sp == 1) return b;
    double r2 = r1 - (double)(float)b;
    return (bf16_t)(float)r2;
}

// ---------------------------------------------------------------------------
// Build all canonical buffers. Layouts (chunk-major so MFMA fragment loads
// are contiguous 16 B/lane):
//  WB  [4 groups][32 jt][3 sp][16 c][16 r][32 kk]   groups: Rc, Zc, NI, NH
//  W0  [3 groups][32 jt][3 sp][16 c][16 r][32 kk]   wh-only: r, z, n rows
//  PB  [7 vt][2 sp][16 c][16 r][32 kk]
//  BB  [4][512] f64: bih_r+bhh_r, bih_z+bhh_z, bih_n, bhh_n
//  gi0 [1536] f64 = x0 @ w_ih^T  (x0 = embed row 0)
__global__ __launch_bounds__(256) void convert_kernel(
    const void* __restrict__ feat, const void* __restrict__ embed,
    const void* __restrict__ wih,  const void* __restrict__ whh,
    const void* __restrict__ bih,  const void* __restrict__ bhh,
    const void* __restrict__ pw,   const void* __restrict__ pb,
    int* __restrict__ flag, int* __restrict__ cnt, int* __restrict__ sense,
    bf16_t* __restrict__ WB, bf16_t* __restrict__ W0, bf16_t* __restrict__ PB,
    bf16_t* __restrict__ hsp, double* __restrict__ hf,
    double* __restrict__ BB, double* __restrict__ pbd, double* __restrict__ gi0)
{
    // runtime dtype detection on feat (~N(0,1)): bf16 buffer -> low u16 of a
    // u32 is a plausible bf16 (~128/128 hits); f32 -> mantissa bits (~15/128).
    __shared__ int s_cnt;
    if (threadIdx.x == 0) s_cnt = 0;
    __syncthreads();
    if (threadIdx.x < 128) {
        unsigned w = ((const unsigned*)feat)[threadIdx.x];
        unsigned e = (w >> 7) & 0xFFu;
        if (e >= 0x68u && e <= 0x85u) atomicAdd(&s_cnt, 1);
    }
    __syncthreads();
    const int isf32 = (s_cnt < 96) ? 1 : 0;
    if (blockIdx.x == 0 && threadIdx.x == 0) {
        *flag = isf32;
        *cnt = 0;      // barrier state: MUST be re-zeroed every call
        *sense = 0;
    }

    const long S0 = NF_;          // feat -> hf[0] + hsp[0] splits
    const long S1 = 3145728;      // WB
    const long S2 = 2359296;      // W0
    const long S3 = 114688;       // PB
    const long S4 = 2048;         // BB
    const long S5 = 100;          // pbd
    const long S6 = 1536;         // gi0
    const long TOT = S0 + S1 + S2 + S3 + S4 + S5 + S6;

    for (long g = blockIdx.x * 256L + threadIdx.x; g < TOT;
         g += (long)gridDim.x * 256L) {
        long i = g;
        if (i < S0) {
            double v = (double)ld_in(feat, i, isf32);
            hf[i] = v;
            hsp[i] = split_pick(v, 0);
            hsp[NF_ + i] = split_pick(v, 1);
            hsp[2 * NF_ + i] = split_pick(v, 2);
            continue;
        }
        i -= S0;
        if (i < S1) {
            long slab = i / SLAB_;  long rem = i % SLAB_;
            int grp = (int)(slab >> 5), jt = (int)(slab & 31);
            int sp = (int)(rem / 8192); long r2 = rem % 8192;
            int c = (int)(r2 / 512), r = (int)((r2 % 512) / 32), kk = (int)(r2 & 31);
            long n = jt * 16 + r, k = c * 32 + kk;
            double v;
            if (grp == 0)      v = (double)ld_in(wih, n * H_ + k, isf32) +
                                   (double)ld_in(whh, n * H_ + k, isf32);
            else if (grp == 1) v = (double)ld_in(wih, (512 + n) * H_ + k, isf32) +
                                   (double)ld_in(whh, (512 + n) * H_ + k, isf32);
            else if (grp == 2) v = (double)ld_in(wih, (1024 + n) * H_ + k, isf32);
            else               v = (double)ld_in(whh, (1024 + n) * H_ + k, isf32);
            WB[i] = split_pick(v, sp);
            continue;
        }
        i -= S1;
        if (i < S2) {
            long slab = i / SLAB_;  long rem = i % SLAB_;
            int grp = (int)(slab >> 5), jt = (int)(slab & 31);
            int sp = (int)(rem / 8192); long r2 = rem % 8192;
            int c = (int)(r2 / 512), r = (int)((r2 % 512) / 32), kk = (int)(r2 & 31);
            long n = jt * 16 + r, k = c * 32 + kk;
            long row = (grp == 0) ? n : (grp == 1) ? (512 + n) : (1024 + n);
            double v = (double)ld_in(whh, row * H_ + k, isf32);
            W0[i] = split_pick(v, sp);
            continue;
        }
        i -= S2;
        if (i < S3) {
            int vt = (int)(i / 16384); long rem = i % 16384;
            int sp = (int)(rem / 8192); long r2 = rem % 8192;
            int c = (int)(r2 / 512), r = (int)((r2 % 512) / 32), kk = (int)(r2 & 31);
            int v = vt * 16 + r;
            long k = c * 32 + kk;
            double val = (v < V_) ? (double)ld_in(pw, (long)v * H_ + k, isf32) : 0.0;
            PB[i] = split_pick(val, sp);
            continue;
        }
        i -= S3;
        if (i < S4) {
            int grp = (int)(i / 512), j = (int)(i & 511);
            double v;
            if (grp == 0)      v = (double)ld_in(bih, j, isf32) + (double)ld_in(bhh, j, isf32);
            else if (grp == 1) v = (double)ld_in(bih, 512 + j, isf32) + (double)ld_in(bhh, 512 + j, isf32);
            else if (grp == 2) v = (double)ld_in(bih, 1024 + j, isf32);
            else               v = (double)ld_in(bhh, 1024 + j, isf32);
            BB[i] = v;
            continue;
        }
        i -= S4;
        if (i < S5) { pbd[i] = (double)ld_in(pb, i, isf32); continue; }
        i -= S5;
        if (i < S6) {
            double acc = 0.0;
            for (int k = 0; k < H_; ++k)
                acc += (double)ld_in(embed, k, isf32) *
                       (double)ld_in(wih, i * H_ + k, isf32);
            gi0[i] = acc;
        }
    }
}

// ---------------------------------------------------------------------------
// Persistent kernel: 256 blocks (1/CU) x 256 threads. Block b: j-tile
// jt = b>>3 (16 cols), m-slice mh = b&7 (32 rows). Wave w owns gate group w
// (Rc, Zc, NI, NH) for both 16-row m-tiles; groups combine via LDS; grid
// barrier (epoch counter + sense) between steps. Blocks 0..111 also project
// h_{s-1} (wave s&3) -> out[:, :, s-1].
__global__ __launch_bounds__(256) void gru_persist(
    const bf16_t* __restrict__ WB, const bf16_t* __restrict__ W0,
    const bf16_t* __restrict__ PB,
    bf16_t* __restrict__ hsp,      // [2 pp][3 sp][NF_]
    double* __restrict__ hf,       // [2 pp][NF_]
    const double* __restrict__ BB, const double* __restrict__ pbd,
    const double* __restrict__ gi0,
    const int* __restrict__ flag, int* __restrict__ cnt, int* __restrict__ sense,
    void* __restrict__ outp)
{
    __shared__ double Gm[4][32][16];

    const int tid = threadIdx.x;
    const int w = tid >> 6;
    const int lane = tid & 63;
    const int ln = lane & 15;
    const int quad = lane >> 4;
    const int b = blockIdx.x;
    const int jt = b >> 3;
    const int m0base = (b & 7) * 32;
    const int isf32 = *flag;

    const long ar0 = (long)(m0base + ln) * H_ + quad * 8;        // m-tile 0
    const long ar1 = (long)(m0base + 16 + ln) * H_ + quad * 8;   // m-tile 1

    for (int s = 0; s <= T_; ++s) {
        const bf16_t* hin = hsp + (long)(s & 1) * 3 * NF_;

        if (s < T_) {
            // ---- GEMM phase: group w, 16 K-chunks ----
            const bf16_t* wb;
            bool skip = false;
            if (s == 0) {
                if (w == 2) skip = true;                  // NI at s=0 comes from gi0
                int gg = (w == 3) ? 2 : w;
                wb = W0 + (long)(gg * 32 + jt) * SLAB_;
            } else {
                wb = WB + (long)(w * 32 + jt) * SLAB_;
            }
            const bf16_t* wp = wb + ln * 32 + quad * 8;

            double dg0[4] = {0, 0, 0, 0}, dg1[4] = {0, 0, 0, 0};
            if (!skip) {
                bf16x8 A0[3], A1[3], Bv[3], nA0[3], nA1[3], nB[3];
                #pragma unroll
                for (int sp = 0; sp < 3; ++sp) {
                    A0[sp] = *(const bf16x8*)(hin + sp * NF_ + ar0);
                    A1[sp] = *(const bf16x8*)(hin + sp * NF_ + ar1);
                    Bv[sp] = *(const bf16x8*)(wp + sp * 8192);
                }
                #pragma unroll
                for (int c = 0; c < 16; ++c) {
                    if (c < 15) {
                        #pragma unroll
                        for (int sp = 0; sp < 3; ++sp) {
                            nA0[sp] = *(const bf16x8*)(hin + sp * NF_ + ar0 + (c + 1) * 32);
                            nA1[sp] = *(const bf16x8*)(hin + sp * NF_ + ar1 + (c + 1) * 32);
                            nB[sp]  = *(const bf16x8*)(wp + sp * 8192 + (c + 1) * 512);
                        }
                    }
                    f32x4 t0 = {0.f, 0.f, 0.f, 0.f};
                    t0 = MFMA(A0[0], Bv[2], t0);
                    t0 = MFMA(A0[1], Bv[1], t0);
                    t0 = MFMA(A0[2], Bv[0], t0);
                    t0 = MFMA(A0[0], Bv[1], t0);
                    t0 = MFMA(A0[1], Bv[0], t0);
                    t0 = MFMA(A0[0], Bv[0], t0);
                    f32x4 t1 = {0.f, 0.f, 0.f, 0.f};
                    t1 = MFMA(A1[0], Bv[2], t1);
                    t1 = MFMA(A1[1], Bv[1], t1);
                    t1 = MFMA(A1[2], Bv[0], t1);
                    t1 = MFMA(A1[0], Bv[1], t1);
                    t1 = MFMA(A1[1], Bv[0], t1);
                    t1 = MFMA(A1[0], Bv[0], t1);
                    #pragma unroll
                    for (int i = 0; i < 4; ++i) {
                        dg0[i] += (double)t0[i];
                        dg1[i] += (double)t1[i];
                    }
                    if (c < 15) {
                        #pragma unroll
                        for (int sp = 0; sp < 3; ++sp) {
                            A0[sp] = nA0[sp]; A1[sp] = nA1[sp]; Bv[sp] = nB[sp];
                        }
                    }
                }
            }
            #pragma unroll
            for (int i = 0; i < 4; ++i) {
                Gm[w][quad * 4 + i][ln] = dg0[i];
                Gm[w][16 + quad * 4 + i][ln] = dg1[i];
            }
            __syncthreads();

            // ---- gate phase: 512 outputs, 2 per thread, all f64 ----
            const double* hfin = hf + (long)(s & 1) * NF_;
            double* hfout = hf + (long)((s + 1) & 1) * NF_;
            bf16_t* ho = hsp + (long)((s + 1) & 1) * 3 * NF_;
            for (int e = tid; e < 512; e += 256) {
                const int m_l = e >> 4, j_l = e & 15;
                const int j = jt * 16 + j_l;
                const long oi = (long)(m0base + m_l) * H_ + j;
                double R  = Gm[0][m_l][j_l] + BB[j];
                double Z  = Gm[1][m_l][j_l] + BB[512 + j];
                double NI = Gm[2][m_l][j_l] + BB[1024 + j];
                double NH = Gm[3][m_l][j_l] + BB[1536 + j];
                if (s == 0) { R += gi0[j]; Z += gi0[512 + j]; NI += gi0[1024 + j]; }
                const double r = 1.0 / (1.0 + exp(-R));
                const double z = 1.0 / (1.0 + exp(-Z));
                const double pre = NI + r * NH;
                const double n = 1.0 - 2.0 / (exp(2.0 * pre) + 1.0);   // tanh
                const double hv = (1.0 - z) * n + z * hfin[oi];
                hfout[oi] = hv;
                bf16_t q1 = (bf16_t)(float)hv;  double r1 = hv - (double)(float)q1;
                bf16_t q2 = (bf16_t)(float)r1;  double r2 = r1 - (double)(float)q2;
                ho[oi] = q1;
                ho[NF_ + oi] = q2;
                ho[2 * NF_ + oi] = (bf16_t)(float)r2;
            }
        }

        // ---- projection of h_{s-1} (= hin) at out column s-1 ----
        if (s >= 1 && b < 112 && w == (s & 3)) {
            const int vtp = b % 7, mtp = b / 7;
            const bf16_t* pa1 = hin + (long)(mtp * 16 + ln) * H_ + quad * 8;
            const bf16_t* pa2 = pa1 + NF_;
            const bf16_t* pb1 = PB + (long)vtp * 16384 + ln * 32 + quad * 8;
            const bf16_t* pb2 = pb1 + 8192;
            f32x4 acc = {0.f, 0.f, 0.f, 0.f};
            #pragma unroll
            for (int c = 0; c < 16; ++c) {
                bf16x8 a1v = *(const bf16x8*)(pa1 + c * 32);
                bf16x8 a2v = *(const bf16x8*)(pa2 + c * 32);
                bf16x8 b1v = *(const bf16x8*)(pb1 + c * 512);
                bf16x8 b2v = *(const bf16x8*)(pb2 + c * 512);
                acc = MFMA(a1v, b2v, acc);
                acc = MFMA(a2v, b1v, acc);
                acc = MFMA(a1v, b1v, acc);
            }
            const int v = vtp * 16 + ln;
            if (v < V_) {
                const double pbv = pbd[v];
                #pragma unroll
                for (int i = 0; i < 4; ++i) {
                    const int m = mtp * 16 + quad * 4 + i;
                    const long idx = ((long)m * V_ + v) * T_ + (s - 1);
                    const float val = (float)((double)acc[i] + pbv);
                    if (isf32) ((float*)outp)[idx] = val;
                    else       ((bf16_t*)outp)[idx] = (bf16_t)val;
                }
            }
        }

        // ---- grid barrier (epoch s+1) ----
        if (s < T_) {
            __syncthreads();
            if (tid == 0) {
                __threadfence();                       // release this block's h writes
                int old = atomicAdd(cnt, 1);           // device-scope by default
                if (old == NBLK_ * (s + 1) - 1)
                    __hip_atomic_store(sense, s + 1, __ATOMIC_RELEASE,
                                       __HIP_MEMORY_SCOPE_AGENT);
                int lim = 0;
                while (__hip_atomic_load(sense, __ATOMIC_ACQUIRE,
                                         __HIP_MEMORY_SCOPE_AGENT) < s + 1) {
                    __builtin_amdgcn_s_sleep(2);
                    if (++lim > 50000000) break;       // failsafe: no hang
                }
            }
            __syncthreads();
        }
    }
}

// ---------------------------------------------------------------------------
extern "C" void kernel_launch(void* const* d_in, const int* in_sizes, int n_in,
                              void* d_out, int out_size, void* d_ws, size_t ws_size,
                              hipStream_t stream) {
    char* ws = (char*)d_ws;
    int*    cnt   = (int*)(ws + 0);
    int*    sense = (int*)(ws + 8);
    int*    flag  = (int*)(ws + 16);
    bf16_t* WB  = (bf16_t*)(ws + 256);          // 6,291,456 B
    bf16_t* W0  = (bf16_t*)(ws + 6291712);      // 4,718,592 B
    bf16_t* PB  = (bf16_t*)(ws + 11010304);     //   458,752 B
    bf16_t* hsp = (bf16_t*)(ws + 11469056);     // 1,572,864 B
    double* hf  = (double*)(ws + 13041920);     // 2,097,152 B
    double* BB  = (double*)(ws + 15139072);     //    16,384 B
    double* pbd = (double*)(ws + 15155456);     //     1,024 B
    double* gi0 = (double*)(ws + 15156480);     //    12,288 B  (end ~14.5 MB)

    convert_kernel<<<1024, 256, 0, stream>>>(
        d_in[0], d_in[1], d_in[2], d_in[3], d_in[4], d_in[5], d_in[6], d_in[7],
        flag, cnt, sense, WB, W0, PB, hsp, hf, BB, pbd, gi0);

    gru_persist<<<NBLK_, 256, 0, stream>>>(
        WB, W0, PB, hsp, hf, BB, pbd, gi0, flag, cnt, sense, d_out);
}

// Round 6
// 8801.509 us; speedup vs baseline: 1.3702x; 1.3702x over previous
//
#include <hip/hip_runtime.h>
#include <hip/hip_bf16.h>
#include <math.h>

// CaptionModel: 200-step GRU (B=256,H=512) + projection V=100.
// Round-6: persistent kernel + XCD-AWARE WORK SWIZZLE. Round-5 counters:
// FETCH 5.6 GB/dispatch = 31 MB/step (HBM-bound, 60 us/step) because with
// jt=b>>3, mh=b&7 each XCD (b%8 round-robin) needed all 32 jt weight slabs
// (6.3 MB > 4 MB L2) -> thrash. Now each XCD owns 8 jt x 4 mh:
//   x=b&7, l=b>>3; jt=(x&3)*8+(l&7); mh=(x>>2)*4+(l>>3)
// per-XCD set = 1.57 MB W + 0.8 MB hsp + 1 MB hf (block-private) < 4 MB L2.
// Projection: blocks jt<14 project their OWN mh rows (L2-local).
// Numerics bit-identical to round 4/5 (passed, absmax 0.0078):
// 3-way bf16 splits, zeroed f32 MFMA chains per K=32 chunk, f64 combine,
// f64 gates, f64 h carry. s>=1 uses precombined (w_ih+w_hh) for r,z.

typedef __bf16 bf16_t;
typedef __bf16 bf16x8 __attribute__((ext_vector_type(8)));
typedef float f32x4 __attribute__((ext_vector_type(4)));

#define B_ 256
#define H_ 512
#define V_ 100
#define T_ 200
#define NF_ 131072              // B_*H_
#define SLAB_ 24576             // 3 splits * 16 chunks * 16 rows * 32 k
#define NBLK_ 256
#define MFMA(a,b,c) __builtin_amdgcn_mfma_f32_16x16x32_bf16((a),(b),(c),0,0,0)

__device__ __forceinline__ float ld_in(const void* p, long i, int isf32) {
    return isf32 ? ((const float*)p)[i] : (float)((const bf16_t*)p)[i];
}

__device__ __forceinline__ bf16_t split_pick(double v, int sp) {
    bf16_t a = (bf16_t)(float)v;
    if (sp == 0) return a;
    double r1 = v - (double)(float)a;
    bf16_t b = (bf16_t)(float)r1;
    if (sp == 1) return b;
    double r2 = r1 - (double)(float)b;
    return (bf16_t)(float)r2;
}

// ---------------------------------------------------------------------------
// Canonical buffers (chunk-major so MFMA fragment loads are 16 B/lane):
//  WB  [4 groups][32 jt][3 sp][16 c][16 r][32 kk]   groups: Rc, Zc, NI, NH
//  W0  [3 groups][32 jt][3 sp][16 c][16 r][32 kk]   wh-only (s==0)
//  PB  [7 vt][2 sp][16 c][16 r][32 kk]
//  BB  [4][512] f64: br_c, bz_c, bn_i, bn_h;  gi0[1536] = x0 @ w_ih^T
__global__ __launch_bounds__(256) void convert_kernel(
    const void* __restrict__ feat, const void* __restrict__ embed,
    const void* __restrict__ wih,  const void* __restrict__ whh,
    const void* __restrict__ bih,  const void* __restrict__ bhh,
    const void* __restrict__ pw,   const void* __restrict__ pb,
    int* __restrict__ flag, int* __restrict__ cnt, int* __restrict__ sense,
    bf16_t* __restrict__ WB, bf16_t* __restrict__ W0, bf16_t* __restrict__ PB,
    bf16_t* __restrict__ hsp, double* __restrict__ hf,
    double* __restrict__ BB, double* __restrict__ pbd, double* __restrict__ gi0)
{
    // runtime dtype detection on feat (~N(0,1)): bf16 buffer -> low u16 of a
    // u32 is a plausible bf16 (~128/128 hits); f32 -> mantissa bits (~15/128).
    __shared__ int s_cnt;
    if (threadIdx.x == 0) s_cnt = 0;
    __syncthreads();
    if (threadIdx.x < 128) {
        unsigned w = ((const unsigned*)feat)[threadIdx.x];
        unsigned e = (w >> 7) & 0xFFu;
        if (e >= 0x68u && e <= 0x85u) atomicAdd(&s_cnt, 1);
    }
    __syncthreads();
    const int isf32 = (s_cnt < 96) ? 1 : 0;
    if (blockIdx.x == 0 && threadIdx.x == 0) {
        *flag = isf32;
        *cnt = 0;      // barrier state: re-zeroed every call (graph-safe)
        *sense = 0;
    }

    const long S0 = NF_;
    const long S1 = 3145728;      // WB
    const long S2 = 2359296;      // W0
    const long S3 = 114688;       // PB
    const long S4 = 2048;         // BB
    const long S5 = 100;          // pbd
    const long S6 = 1536;         // gi0
    const long TOT = S0 + S1 + S2 + S3 + S4 + S5 + S6;

    for (long g = blockIdx.x * 256L + threadIdx.x; g < TOT;
         g += (long)gridDim.x * 256L) {
        long i = g;
        if (i < S0) {
            double v = (double)ld_in(feat, i, isf32);
            hf[i] = v;
            hsp[i] = split_pick(v, 0);
            hsp[NF_ + i] = split_pick(v, 1);
            hsp[2 * NF_ + i] = split_pick(v, 2);
            continue;
        }
        i -= S0;
        if (i < S1) {
            long slab = i / SLAB_;  long rem = i % SLAB_;
            int grp = (int)(slab >> 5), jt = (int)(slab & 31);
            int sp = (int)(rem / 8192); long r2 = rem % 8192;
            int c = (int)(r2 / 512), r = (int)((r2 % 512) / 32), kk = (int)(r2 & 31);
            long n = jt * 16 + r, k = c * 32 + kk;
            double v;
            if (grp == 0)      v = (double)ld_in(wih, n * H_ + k, isf32) +
                                   (double)ld_in(whh, n * H_ + k, isf32);
            else if (grp == 1) v = (double)ld_in(wih, (512 + n) * H_ + k, isf32) +
                                   (double)ld_in(whh, (512 + n) * H_ + k, isf32);
            else if (grp == 2) v = (double)ld_in(wih, (1024 + n) * H_ + k, isf32);
            else               v = (double)ld_in(whh, (1024 + n) * H_ + k, isf32);
            WB[i] = split_pick(v, sp);
            continue;
        }
        i -= S1;
        if (i < S2) {
            long slab = i / SLAB_;  long rem = i % SLAB_;
            int grp = (int)(slab >> 5), jt = (int)(slab & 31);
            int sp = (int)(rem / 8192); long r2 = rem % 8192;
            int c = (int)(r2 / 512), r = (int)((r2 % 512) / 32), kk = (int)(r2 & 31);
            long n = jt * 16 + r, k = c * 32 + kk;
            long row = (grp == 0) ? n : (grp == 1) ? (512 + n) : (1024 + n);
            double v = (double)ld_in(whh, row * H_ + k, isf32);
            W0[i] = split_pick(v, sp);
            continue;
        }
        i -= S2;
        if (i < S3) {
            int vt = (int)(i / 16384); long rem = i % 16384;
            int sp = (int)(rem / 8192); long r2 = rem % 8192;
            int c = (int)(r2 / 512), r = (int)((r2 % 512) / 32), kk = (int)(r2 & 31);
            int v = vt * 16 + r;
            long k = c * 32 + kk;
            double val = (v < V_) ? (double)ld_in(pw, (long)v * H_ + k, isf32) : 0.0;
            PB[i] = split_pick(val, sp);
            continue;
        }
        i -= S3;
        if (i < S4) {
            int grp = (int)(i / 512), j = (int)(i & 511);
            double v;
            if (grp == 0)      v = (double)ld_in(bih, j, isf32) + (double)ld_in(bhh, j, isf32);
            else if (grp == 1) v = (double)ld_in(bih, 512 + j, isf32) + (double)ld_in(bhh, 512 + j, isf32);
            else if (grp == 2) v = (double)ld_in(bih, 1024 + j, isf32);
            else               v = (double)ld_in(bhh, 1024 + j, isf32);
            BB[i] = v;
            continue;
        }
        i -= S4;
        if (i < S5) { pbd[i] = (double)ld_in(pb, i, isf32); continue; }
        i -= S5;
        if (i < S6) {
            double acc = 0.0;
            for (int k = 0; k < H_; ++k)
                acc += (double)ld_in(embed, k, isf32) *
                       (double)ld_in(wih, i * H_ + k, isf32);
            gi0[i] = acc;
        }
    }
}

// ---------------------------------------------------------------------------
// Persistent kernel: 256 blocks (1/CU) x 256 threads.
// XCD swizzle (assumes round-robin blockIdx%8 -> XCD): each XCD owns
// 8 jt x 4 mh so its weight+h working set (~3.4 MB) fits its 4 MB L2.
__global__ __launch_bounds__(256) void gru_persist(
    const bf16_t* __restrict__ WB, const bf16_t* __restrict__ W0,
    const bf16_t* __restrict__ PB,
    bf16_t* __restrict__ hsp,      // [2 pp][3 sp][NF_]
    double* __restrict__ hf,       // [2 pp][NF_]
    const double* __restrict__ BB, const double* __restrict__ pbd,
    const double* __restrict__ gi0,
    const int* __restrict__ flag, int* __restrict__ cnt, int* __restrict__ sense,
    void* __restrict__ outp)
{
    __shared__ double Gm[4][32][16];

    const int tid = threadIdx.x;
    const int w = tid >> 6;
    const int lane = tid & 63;
    const int ln = lane & 15;
    const int quad = lane >> 4;
    const int b = blockIdx.x;
    // ---- XCD-aware swizzle ----
    const int x = b & 7;        // assumed XCD (round-robin dispatch)
    const int l = b >> 3;       // 0..31 within XCD
    const int jt = (x & 3) * 8 + (l & 7);          // 8 jt per XCD
    const int mh = (x >> 2) * 4 + (l >> 3);        // 4 mh per XCD
    const int m0base = mh * 32;
    const int isf32 = *flag;

    const long ar0 = (long)(m0base + ln) * H_ + quad * 8;        // m-tile 0
    const long ar1 = (long)(m0base + 16 + ln) * H_ + quad * 8;   // m-tile 1

    for (int s = 0; s <= T_; ++s) {
        const bf16_t* hin = hsp + (long)(s & 1) * 3 * NF_;

        if (s < T_) {
            // ---- GEMM phase: group w, 16 K-chunks ----
            const bf16_t* wb;
            bool skip = false;
            if (s == 0) {
                if (w == 2) skip = true;                  // NI at s=0 from gi0
                int gg = (w == 3) ? 2 : w;
                wb = W0 + (long)(gg * 32 + jt) * SLAB_;
            } else {
                wb = WB + (long)(w * 32 + jt) * SLAB_;
            }
            const bf16_t* wp = wb + ln * 32 + quad * 8;

            double dg0[4] = {0, 0, 0, 0}, dg1[4] = {0, 0, 0, 0};
            if (!skip) {
                bf16x8 A0[3], A1[3], Bv[3], nA0[3], nA1[3], nB[3];
                #pragma unroll
                for (int sp = 0; sp < 3; ++sp) {
                    A0[sp] = *(const bf16x8*)(hin + sp * NF_ + ar0);
                    A1[sp] = *(const bf16x8*)(hin + sp * NF_ + ar1);
                    Bv[sp] = *(const bf16x8*)(wp + sp * 8192);
                }
                #pragma unroll
                for (int c = 0; c < 16; ++c) {
                    if (c < 15) {
                        #pragma unroll
                        for (int sp = 0; sp < 3; ++sp) {
                            nA0[sp] = *(const bf16x8*)(hin + sp * NF_ + ar0 + (c + 1) * 32);
                            nA1[sp] = *(const bf16x8*)(hin + sp * NF_ + ar1 + (c + 1) * 32);
                            nB[sp]  = *(const bf16x8*)(wp + sp * 8192 + (c + 1) * 512);
                        }
                    }
                    f32x4 t0 = {0.f, 0.f, 0.f, 0.f};
                    t0 = MFMA(A0[0], Bv[2], t0);
                    t0 = MFMA(A0[1], Bv[1], t0);
                    t0 = MFMA(A0[2], Bv[0], t0);
                    t0 = MFMA(A0[0], Bv[1], t0);
                    t0 = MFMA(A0[1], Bv[0], t0);
                    t0 = MFMA(A0[0], Bv[0], t0);
                    f32x4 t1 = {0.f, 0.f, 0.f, 0.f};
                    t1 = MFMA(A1[0], Bv[2], t1);
                    t1 = MFMA(A1[1], Bv[1], t1);
                    t1 = MFMA(A1[2], Bv[0], t1);
                    t1 = MFMA(A1[0], Bv[1], t1);
                    t1 = MFMA(A1[1], Bv[0], t1);
                    t1 = MFMA(A1[0], Bv[0], t1);
                    #pragma unroll
                    for (int i = 0; i < 4; ++i) {
                        dg0[i] += (double)t0[i];
                        dg1[i] += (double)t1[i];
                    }
                    if (c < 15) {
                        #pragma unroll
                        for (int sp = 0; sp < 3; ++sp) {
                            A0[sp] = nA0[sp]; A1[sp] = nA1[sp]; Bv[sp] = nB[sp];
                        }
                    }
                }
            }
            #pragma unroll
            for (int i = 0; i < 4; ++i) {
                Gm[w][quad * 4 + i][ln] = dg0[i];
                Gm[w][16 + quad * 4 + i][ln] = dg1[i];
            }
            __syncthreads();

            // ---- gate phase: 512 outputs, 2 per thread, all f64 ----
            const double* hfin = hf + (long)(s & 1) * NF_;
            double* hfout = hf + (long)((s + 1) & 1) * NF_;
            bf16_t* ho = hsp + (long)((s + 1) & 1) * 3 * NF_;
            for (int e = tid; e < 512; e += 256) {
                const int m_l = e >> 4, j_l = e & 15;
                const int j = jt * 16 + j_l;
                const long oi = (long)(m0base + m_l) * H_ + j;
                double R  = Gm[0][m_l][j_l] + BB[j];
                double Z  = Gm[1][m_l][j_l] + BB[512 + j];
                double NI = Gm[2][m_l][j_l] + BB[1024 + j];
                double NH = Gm[3][m_l][j_l] + BB[1536 + j];
                if (s == 0) { R += gi0[j]; Z += gi0[512 + j]; NI += gi0[1024 + j]; }
                const double r = 1.0 / (1.0 + exp(-R));
                const double z = 1.0 / (1.0 + exp(-Z));
                const double pre = NI + r * NH;
                const double n = 1.0 - 2.0 / (exp(2.0 * pre) + 1.0);   // tanh
                const double hv = (1.0 - z) * n + z * hfin[oi];
                hfout[oi] = hv;
                bf16_t q1 = (bf16_t)(float)hv;  double r1 = hv - (double)(float)q1;
                bf16_t q2 = (bf16_t)(float)r1;  double r2 = r1 - (double)(float)q2;
                ho[oi] = q1;
                ho[NF_ + oi] = q2;
                ho[2 * NF_ + oi] = (bf16_t)(float)r2;
            }
        }

        // ---- projection of h_{s-1} (= hin) at out column s-1 ----
        // Blocks with jt<14 project their OWN mh rows: L2-local A reads.
        if (s >= 1 && jt < 14 && w == (s & 3)) {
            const int mtp = mh * 2 + (jt & 1);     // 0..15
            const int vtp = jt >> 1;               // 0..6
            const bf16_t* pa1 = hin + (long)(mtp * 16 + ln) * H_ + quad * 8;
            const bf16_t* pa2 = pa1 + NF_;
            const bf16_t* pb1 = PB + (long)vtp * 16384 + ln * 32 + quad * 8;
            const bf16_t* pb2 = pb1 + 8192;
            f32x4 acc = {0.f, 0.f, 0.f, 0.f};
            #pragma unroll
            for (int c = 0; c < 16; ++c) {
                bf16x8 a1v = *(const bf16x8*)(pa1 + c * 32);
                bf16x8 a2v = *(const bf16x8*)(pa2 + c * 32);
                bf16x8 b1v = *(const bf16x8*)(pb1 + c * 512);
                bf16x8 b2v = *(const bf16x8*)(pb2 + c * 512);
                acc = MFMA(a1v, b2v, acc);
                acc = MFMA(a2v, b1v, acc);
                acc = MFMA(a1v, b1v, acc);
            }
            const int v = vtp * 16 + ln;
            if (v < V_) {
                const double pbv = pbd[v];
                #pragma unroll
                for (int i = 0; i < 4; ++i) {
                    const int m = mtp * 16 + quad * 4 + i;
                    const long idx = ((long)m * V_ + v) * T_ + (s - 1);
                    const float val = (float)((double)acc[i] + pbv);
                    if (isf32) ((float*)outp)[idx] = val;
                    else       ((bf16_t*)outp)[idx] = (bf16_t)val;
                }
            }
        }

        // ---- grid barrier (epoch s+1) ----
        if (s < T_) {
            __syncthreads();
            if (tid == 0) {
                __threadfence();                       // release h writes
                int old = atomicAdd(cnt, 1);           // device-scope
                if (old == NBLK_ * (s + 1) - 1)
                    __hip_atomic_store(sense, s + 1, __ATOMIC_RELEASE,
                                       __HIP_MEMORY_SCOPE_AGENT);
                int lim = 0;
                while (__hip_atomic_load(sense, __ATOMIC_ACQUIRE,
                                         __HIP_MEMORY_SCOPE_AGENT) < s + 1) {
                    __builtin_amdgcn_s_sleep(2);
                    if (++lim > 50000000) break;       // failsafe: no hang
                }
            }
            __syncthreads();
        }
    }
}

// ---------------------------------------------------------------------------
extern "C" void kernel_launch(void* const* d_in, const int* in_sizes, int n_in,
                              void* d_out, int out_size, void* d_ws, size_t ws_size,
                              hipStream_t stream) {
    char* ws = (char*)d_ws;
    int*    cnt   = (int*)(ws + 0);
    int*    sense = (int*)(ws + 8);
    int*    flag  = (int*)(ws + 16);
    bf16_t* WB  = (bf16_t*)(ws + 256);          // 6,291,456 B
    bf16_t* W0  = (bf16_t*)(ws + 6291712);      // 4,718,592 B
    bf16_t* PB  = (bf16_t*)(ws + 11010304);     //   458,752 B
    bf16_t* hsp = (bf16_t*)(ws + 11469056);     // 1,572,864 B
    double* hf  = (double*)(ws + 13041920);     // 2,097,152 B
    double* BB  = (double*)(ws + 15139072);     //    16,384 B
    double* pbd = (double*)(ws + 15155456);     //     1,024 B
    double* gi0 = (double*)(ws + 15156480);     //    12,288 B  (end ~14.5 MB)

    convert_kernel<<<1024, 256, 0, stream>>>(
        d_in[0], d_in[1], d_in[2], d_in[3], d_in[4], d_in[5], d_in[6], d_in[7],
        flag, cnt, sense, WB, W0, PB, hsp, hf, BB, pbd, gi0);

    gru_persist<<<NBLK_, 256, 0, stream>>>(
        WB, W0, PB, hsp, hf, BB, pbd, gi0, flag, cnt, sense, d_out);
}

// Round 7
// 3291.053 us; speedup vs baseline: 3.6645x; 2.6744x over previous
//
#include <hip/hip_runtime.h>
#include <hip/hip_bf16.h>
#include <math.h>

// CaptionModel: 200-step GRU (B=256,H=512) + projection V=100.
// Round-7: persistent kernel, NO agent-scope cache maintenance in the loop.
// Round-6 counters (44 us/step, 3% util, HBM quiet) => the per-step
// acquire(buffer_inv L2) + threadfence(buffer_wbl2) storm re-fetched the
// whole per-XCD working set from L3 every step at 1 wave/SIMD.
// Now: only hsp crosses XCDs. hsp reads = relaxed agent atomic u64 loads
// (global_load sc1: L2-bypass, coherent, NO inv) staged into LDS once per
// block; hsp writes = relaxed agent atomic u16 stores (write-through, NO
// wbl2). Weights/hf: plain cached loads - L2-resident all 200 steps.
// Barrier: per-mh-group (32 blocks), relaxed atomics; release ordering via
// the compiler's vmcnt(0) drain before s_barrier.
// Numerics bit-identical to rounds 4-6 (absmax 0.0078125 canary):
// 3-way bf16 splits, zeroed f32 MFMA chains per K=32 chunk (fixed order),
// f64 combine/gates/carry. s>=1 r,z use precombined (w_ih+w_hh).

typedef __bf16 bf16_t;
typedef __bf16 bf16x8 __attribute__((ext_vector_type(8)));
typedef float f32x4 __attribute__((ext_vector_type(4)));
typedef unsigned long long u64;
typedef unsigned short u16;

#define B_ 256
#define H_ 512
#define V_ 100
#define T_ 200
#define NF_ 131072              // B_*H_
#define SLAB_ 24576             // per (group,jt): 3 sp * 16 c * 16 r * 32 k
#define MFMA(a,b,c) __builtin_amdgcn_mfma_f32_16x16x32_bf16((a),(b),(c),0,0,0)

__device__ __forceinline__ float ld_in(const void* p, long i, int isf32) {
    return isf32 ? ((const float*)p)[i] : (float)((const bf16_t*)p)[i];
}

__device__ __forceinline__ bf16_t split_pick(double v, int sp) {
    bf16_t a = (bf16_t)(float)v;
    if (sp == 0) return a;
    double r1 = v - (double)(float)a;
    bf16_t b = (bf16_t)(float)r1;
    if (sp == 1) return b;
    double r2 = r1 - (double)(float)b;
    return (bf16_t)(float)r2;
}

union bfbits { __bf16 b; u16 u; };

// ---------------------------------------------------------------------------
// Canonical buffers (chunk-major, MFMA fragment = 16 B/lane):
//  WB [4 grp][32 jt][3 sp][16 c][16 r][32 k]  grps: Rc, Zc, NI, NH
//  W0 [3 grp][32 jt][3 sp][16 c][16 r][32 k]  wh-only (s==0)
//  PB [7 vt][2 sp][16 c][16 r][32 k]
//  BB [4][512] f64; gi0[1536] f64 = x0 @ w_ih^T
__global__ __launch_bounds__(256) void convert_kernel(
    const void* __restrict__ feat, const void* __restrict__ embed,
    const void* __restrict__ wih,  const void* __restrict__ whh,
    const void* __restrict__ bih,  const void* __restrict__ bhh,
    const void* __restrict__ pw,   const void* __restrict__ pb,
    char* __restrict__ barr, int* __restrict__ flag,
    bf16_t* __restrict__ WB, bf16_t* __restrict__ W0, bf16_t* __restrict__ PB,
    bf16_t* __restrict__ hsp, double* __restrict__ hf,
    double* __restrict__ BB, double* __restrict__ pbd, double* __restrict__ gi0)
{
    // runtime dtype detection on feat (~N(0,1)): bf16 buffer -> low u16 of a
    // u32 is a plausible bf16 (~128/128); f32 -> mantissa bits (~15/128).
    __shared__ int s_cnt;
    if (threadIdx.x == 0) s_cnt = 0;
    __syncthreads();
    if (threadIdx.x < 128) {
        unsigned w = ((const unsigned*)feat)[threadIdx.x];
        unsigned e = (w >> 7) & 0xFFu;
        if (e >= 0x68u && e <= 0x85u) atomicAdd(&s_cnt, 1);
    }
    __syncthreads();
    const int isf32 = (s_cnt < 96) ? 1 : 0;
    if (blockIdx.x == 0) {
        if (threadIdx.x == 0) *flag = isf32;
        if (threadIdx.x < 16) {       // zero per-group barrier state (8 cnt + 8 sense)
            int g = threadIdx.x & 7;
            int* p = (int*)(barr + ((threadIdx.x < 8) ? (size_t)g * 128
                                                      : 4096 + (size_t)g * 128));
            *p = 0;
        }
    }

    const long S0 = NF_;
    const long S1 = 3145728;      // WB elems
    const long S2 = 2359296;      // W0
    const long S3 = 114688;       // PB
    const long S4 = 2048;         // BB
    const long S5 = 100;          // pbd
    const long S6 = 1536;         // gi0
    const long TOT = S0 + S1 + S2 + S3 + S4 + S5 + S6;

    for (long g = blockIdx.x * 256L + threadIdx.x; g < TOT;
         g += (long)gridDim.x * 256L) {
        long i = g;
        if (i < S0) {
            double v = (double)ld_in(feat, i, isf32);
            hf[i] = v;
            hsp[i] = split_pick(v, 0);
            hsp[NF_ + i] = split_pick(v, 1);
            hsp[2 * NF_ + i] = split_pick(v, 2);
            continue;
        }
        i -= S0;
        if (i < S1) {
            long slab = i / SLAB_;  long rem = i % SLAB_;
            int grp = (int)(slab >> 5), jt = (int)(slab & 31);
            int sp = (int)(rem / 8192); long r2 = rem % 8192;
            int c = (int)(r2 / 512), r = (int)((r2 % 512) / 32), kk = (int)(r2 & 31);
            long n = jt * 16 + r, k = c * 32 + kk;
            double v;
            if (grp == 0)      v = (double)ld_in(wih, n * H_ + k, isf32) +
                                   (double)ld_in(whh, n * H_ + k, isf32);
            else if (grp == 1) v = (double)ld_in(wih, (512 + n) * H_ + k, isf32) +
                                   (double)ld_in(whh, (512 + n) * H_ + k, isf32);
            else if (grp == 2) v = (double)ld_in(wih, (1024 + n) * H_ + k, isf32);
            else               v = (double)ld_in(whh, (1024 + n) * H_ + k, isf32);
            WB[i] = split_pick(v, sp);
            continue;
        }
        i -= S1;
        if (i < S2) {
            long slab = i / SLAB_;  long rem = i % SLAB_;
            int grp = (int)(slab >> 5), jt = (int)(slab & 31);
            int sp = (int)(rem / 8192); long r2 = rem % 8192;
            int c = (int)(r2 / 512), r = (int)((r2 % 512) / 32), kk = (int)(r2 & 31);
            long n = jt * 16 + r, k = c * 32 + kk;
            long row = (grp == 0) ? n : (grp == 1) ? (512 + n) : (1024 + n);
            W0[i] = split_pick((double)ld_in(whh, row * H_ + k, isf32), sp);
            continue;
        }
        i -= S2;
        if (i < S3) {
            int vt = (int)(i / 16384); long rem = i % 16384;
            int sp = (int)(rem / 8192); long r2 = rem % 8192;
            int c = (int)(r2 / 512), r = (int)((r2 % 512) / 32), kk = (int)(r2 & 31);
            int v = vt * 16 + r;
            long k = c * 32 + kk;
            double val = (v < V_) ? (double)ld_in(pw, (long)v * H_ + k, isf32) : 0.0;
            PB[i] = split_pick(val, sp);
            continue;
        }
        i -= S3;
        if (i < S4) {
            int grp = (int)(i / 512), j = (int)(i & 511);
            double v;
            if (grp == 0)      v = (double)ld_in(bih, j, isf32) + (double)ld_in(bhh, j, isf32);
            else if (grp == 1) v = (double)ld_in(bih, 512 + j, isf32) + (double)ld_in(bhh, 512 + j, isf32);
            else if (grp == 2) v = (double)ld_in(bih, 1024 + j, isf32);
            else               v = (double)ld_in(bhh, 1024 + j, isf32);
            BB[i] = v;
            continue;
        }
        i -= S4;
        if (i < S5) { pbd[i] = (double)ld_in(pb, i, isf32); continue; }
        i -= S5;
        if (i < S6) {
            double acc = 0.0;
            for (int k = 0; k < H_; ++k)
                acc += (double)ld_in(embed, k, isf32) *
                       (double)ld_in(wih, i * H_ + k, isf32);
            gi0[i] = acc;
        }
    }
}

// ---------------------------------------------------------------------------
// Persistent: 256 blocks (1/CU) x 256 threads. XCD swizzle: x=b&7, l=b>>3;
// jt=(x&3)*8+(l&7), mh=(x>>2)*4+(l>>3) -> per-XCD weight set 1.57 MB in L2.
// Per-step: 4 quarters of [reg-prefetch hsp (sc1 u64 atomics) -> LDS ->
// 4 K-chunks of MFMA]. Barrier per mh-group (32 blocks), relaxed atomics.
__global__ __launch_bounds__(256) void gru_persist(
    const bf16_t* __restrict__ WB, const bf16_t* __restrict__ W0,
    const bf16_t* __restrict__ PB,
    bf16_t* __restrict__ hsp,      // [2 pp][3 sp][NF_] - cross-XCD, sc1 only
    double* __restrict__ hf,       // [2 pp][NF_] - block-private, cached
    const double* __restrict__ BB, const double* __restrict__ pbd,
    const double* __restrict__ gi0,
    const int* __restrict__ flag, char* __restrict__ barr,
    void* __restrict__ outp)
{
    __shared__ __align__(16) __bf16 Ast[3][32][136];   // 272-B rows (pad 16 B)
    __shared__ double Gm[4][32][16];

    const int tid = threadIdx.x;
    const int w = tid >> 6;
    const int lane = tid & 63;
    const int ln = lane & 15;
    const int quad = lane >> 4;
    const int b = blockIdx.x;
    const int x = b & 7;                       // assumed XCD (round-robin)
    const int l = b >> 3;
    const int jt = (x & 3) * 8 + (l & 7);
    const int mh = (x >> 2) * 4 + (l >> 3);
    const int m0base = mh * 32;
    const int isf32 = *flag;

    int* myc = (int*)(barr + (size_t)mh * 128);
    int* mys = (int*)(barr + 4096 + (size_t)mh * 128);

    for (int s = 0; s <= T_; ++s) {
        const u64* hin64 = (const u64*)(hsp + (long)(s & 1) * 3 * NF_);

        // GEMM setup
        const bf16_t* wp = nullptr;
        bool gemm = false;
        if (s < T_) {
            bool skip = false;
            const bf16_t* wb;
            if (s == 0) {
                if (w == 2) skip = true;               // NI at s=0 from gi0
                int gg = (w == 3) ? 2 : w;
                wb = W0 + (long)(gg * 32 + jt) * SLAB_;
            } else {
                wb = WB + (long)(w * 32 + jt) * SLAB_;
            }
            wp = wb + ln * 32 + quad * 8;
            gemm = !skip;
        }
        const bool doproj = (s >= 1 && jt < 14 && w == (s & 3));
        const int tpj = jt & 1;                        // proj uses own m-tile
        const bf16_t* pbB1 = PB + (long)(jt >> 1) * 16384 + ln * 32 + quad * 8;
        const bf16_t* pbB2 = pbB1 + 8192;

        double dg0[4] = {0, 0, 0, 0}, dg1[4] = {0, 0, 0, 0};
        f32x4 pacc = {0.f, 0.f, 0.f, 0.f};
        bf16x8 Bc[3], Bn[3];
        if (gemm) {
            #pragma unroll
            for (int sp = 0; sp < 3; ++sp)
                Bc[sp] = *(const bf16x8*)(wp + sp * 8192);   // chunk 0
        }

        // prefetch staging quarter 0 (relaxed agent = sc1, bypasses L2, NO inv)
        u64 sreg[12];
        #pragma unroll
        for (int i = 0; i < 12; ++i) {
            int u = i * 256 + tid;
            int sp = u >> 10, row = (u >> 5) & 31, k8 = u & 31;
            long off64 = (((long)sp * NF_ + (long)(m0base + row) * 512) >> 2) + k8;
            sreg[i] = __hip_atomic_load(hin64 + off64, __ATOMIC_RELAXED,
                                        __HIP_MEMORY_SCOPE_AGENT);
        }

        for (int q = 0; q < 4; ++q) {
            // dump quarter q regs -> LDS
            #pragma unroll
            for (int i = 0; i < 12; ++i) {
                int u = i * 256 + tid;
                int sp = u >> 10, row = (u >> 5) & 31, k8 = u & 31;
                *(u64*)&Ast[sp][row][k8 * 4] = sreg[i];
            }
            // issue quarter q+1 loads (overlap with compute below)
            if (q < 3) {
                #pragma unroll
                for (int i = 0; i < 12; ++i) {
                    int u = i * 256 + tid;
                    int sp = u >> 10, row = (u >> 5) & 31, k8 = u & 31;
                    long off64 = (((long)sp * NF_ + (long)(m0base + row) * 512 +
                                   (q + 1) * 128) >> 2) + k8;
                    sreg[i] = __hip_atomic_load(hin64 + off64, __ATOMIC_RELAXED,
                                                __HIP_MEMORY_SCOPE_AGENT);
                }
            }
            __syncthreads();

            for (int cc = 0; cc < 4; ++cc) {
                const int c = q * 4 + cc;
                if (gemm) {
                    if (c < 15) {
                        #pragma unroll
                        for (int sp = 0; sp < 3; ++sp)
                            Bn[sp] = *(const bf16x8*)(wp + sp * 8192 + (c + 1) * 512);
                    }
                    bf16x8 A0[3], A1[3];
                    #pragma unroll
                    for (int sp = 0; sp < 3; ++sp) {
                        A0[sp] = *(const bf16x8*)&Ast[sp][ln][cc * 32 + quad * 8];
                        A1[sp] = *(const bf16x8*)&Ast[sp][16 + ln][cc * 32 + quad * 8];
                    }
                    f32x4 t0 = {0.f, 0.f, 0.f, 0.f};
                    t0 = MFMA(A0[0], Bc[2], t0);
                    t0 = MFMA(A0[1], Bc[1], t0);
                    t0 = MFMA(A0[2], Bc[0], t0);
                    t0 = MFMA(A0[0], Bc[1], t0);
                    t0 = MFMA(A0[1], Bc[0], t0);
                    t0 = MFMA(A0[0], Bc[0], t0);
                    f32x4 t1 = {0.f, 0.f, 0.f, 0.f};
                    t1 = MFMA(A1[0], Bc[2], t1);
                    t1 = MFMA(A1[1], Bc[1], t1);
                    t1 = MFMA(A1[2], Bc[0], t1);
                    t1 = MFMA(A1[0], Bc[1], t1);
                    t1 = MFMA(A1[1], Bc[0], t1);
                    t1 = MFMA(A1[0], Bc[0], t1);
                    #pragma unroll
                    for (int i = 0; i < 4; ++i) {
                        dg0[i] += (double)t0[i];
                        dg1[i] += (double)t1[i];
                    }
                    if (c < 15) {
                        #pragma unroll
                        for (int sp = 0; sp < 3; ++sp) Bc[sp] = Bn[sp];
                    }
                }
                if (doproj) {
                    bf16x8 pa1 = *(const bf16x8*)&Ast[0][tpj * 16 + ln][cc * 32 + quad * 8];
                    bf16x8 pa2 = *(const bf16x8*)&Ast[1][tpj * 16 + ln][cc * 32 + quad * 8];
                    bf16x8 b1v = *(const bf16x8*)(pbB1 + c * 512);
                    bf16x8 b2v = *(const bf16x8*)(pbB2 + c * 512);
                    pacc = MFMA(pa1, b2v, pacc);
                    pacc = MFMA(pa2, b1v, pacc);
                    pacc = MFMA(pa1, b1v, pacc);
                }
            }
            __syncthreads();     // protect Ast before next quarter's dump
        }

        // projection output (h_{s-1} @ pw^T + pb) at out column s-1
        if (doproj) {
            const int v = (jt >> 1) * 16 + ln;
            if (v < V_) {
                const double pbv = pbd[v];
                const int mtp = mh * 2 + tpj;
                #pragma unroll
                for (int i = 0; i < 4; ++i) {
                    const int m = mtp * 16 + quad * 4 + i;
                    const long idx = ((long)m * V_ + v) * T_ + (s - 1);
                    const float val = (float)((double)pacc[i] + pbv);
                    if (isf32) ((float*)outp)[idx] = val;
                    else       ((bf16_t*)outp)[idx] = (bf16_t)val;
                }
            }
        }

        if (s < T_) {
            #pragma unroll
            for (int i = 0; i < 4; ++i) {
                Gm[w][quad * 4 + i][ln] = dg0[i];
                Gm[w][16 + quad * 4 + i][ln] = dg1[i];
            }
            __syncthreads();

            // gate phase: f64; hf plain (private, cached); hsp via relaxed
            // agent u16 stores (write-through, no wbl2)
            const double* hfin = hf + (long)(s & 1) * NF_;
            double* hfout = hf + (long)((s + 1) & 1) * NF_;
            u16* ho = (u16*)(hsp + (long)((s + 1) & 1) * 3 * NF_);
            for (int e = tid; e < 512; e += 256) {
                const int m_l = e >> 4, j_l = e & 15;
                const int j = jt * 16 + j_l;
                const long oi = (long)(m0base + m_l) * H_ + j;
                double R  = Gm[0][m_l][j_l] + BB[j];
                double Z  = Gm[1][m_l][j_l] + BB[512 + j];
                double NI = Gm[2][m_l][j_l] + BB[1024 + j];
                double NH = Gm[3][m_l][j_l] + BB[1536 + j];
                if (s == 0) { R += gi0[j]; Z += gi0[512 + j]; NI += gi0[1024 + j]; }
                const double r = 1.0 / (1.0 + exp(-R));
                const double z = 1.0 / (1.0 + exp(-Z));
                const double pre = NI + r * NH;
                const double n = 1.0 - 2.0 / (exp(2.0 * pre) + 1.0);   // tanh
                const double hv = (1.0 - z) * n + z * hfin[oi];
                hfout[oi] = hv;
                bfbits q1, q2, q3;
                q1.b = (bf16_t)(float)hv;  double r1 = hv - (double)(float)q1.b;
                q2.b = (bf16_t)(float)r1;  double r2 = r1 - (double)(float)q2.b;
                q3.b = (bf16_t)(float)r2;
                __hip_atomic_store(ho + oi, q1.u, __ATOMIC_RELAXED, __HIP_MEMORY_SCOPE_AGENT);
                __hip_atomic_store(ho + NF_ + oi, q2.u, __ATOMIC_RELAXED, __HIP_MEMORY_SCOPE_AGENT);
                __hip_atomic_store(ho + 2 * NF_ + oi, q3.u, __ATOMIC_RELAXED, __HIP_MEMORY_SCOPE_AGENT);
            }

            // per-group barrier: 32 blocks, relaxed atomics, no cache maint.
            // Release: compiler drains vmcnt before s_barrier; hsp stores are
            // write-through so retirement == L3 visibility.
            __syncthreads();
            if (tid == 0) {
                int old = __hip_atomic_fetch_add(myc, 1, __ATOMIC_RELAXED,
                                                 __HIP_MEMORY_SCOPE_AGENT);
                if (old == 32 * (s + 1) - 1)
                    __hip_atomic_store(mys, s + 1, __ATOMIC_RELAXED,
                                       __HIP_MEMORY_SCOPE_AGENT);
                int lim = 0;
                while (__hip_atomic_load(mys, __ATOMIC_RELAXED,
                                         __HIP_MEMORY_SCOPE_AGENT) < s + 1) {
                    __builtin_amdgcn_s_sleep(2);
                    if (++lim > 100000000) break;      // failsafe: no hang
                }
            }
            __syncthreads();
        }
    }
}

// ---------------------------------------------------------------------------
extern "C" void kernel_launch(void* const* d_in, const int* in_sizes, int n_in,
                              void* d_out, int out_size, void* d_ws, size_t ws_size,
                              hipStream_t stream) {
    char* ws = (char*)d_ws;
    char*   barr = ws;                          // [0,8192): cnt/sense lines
    int*    flag = (int*)(ws + 8192);
    bf16_t* WB  = (bf16_t*)(ws + 8448);         // 6,291,456 B
    bf16_t* W0  = (bf16_t*)(ws + 6299904);      // 4,718,592 B
    bf16_t* PB  = (bf16_t*)(ws + 11018496);     //   458,752 B
    bf16_t* hsp = (bf16_t*)(ws + 11477248);     // 1,572,864 B
    double* hf  = (double*)(ws + 13050112);     // 2,097,152 B
    double* BB  = (double*)(ws + 15147264);     //    16,384 B
    double* pbd = (double*)(ws + 15163648);     //     1,024 B
    double* gi0 = (double*)(ws + 15164672);     //    12,288 B  (end ~14.5 MB)

    convert_kernel<<<1024, 256, 0, stream>>>(
        d_in[0], d_in[1], d_in[2], d_in[3], d_in[4], d_in[5], d_in[6], d_in[7],
        barr, flag, WB, W0, PB, hsp, hf, BB, pbd, gi0);

    gru_persist<<<256, 256, 0, stream>>>(
        WB, W0, PB, hsp, hf, BB, pbd, gi0, flag, barr, d_out);
}

// Round 8
// 2398.387 us; speedup vs baseline: 5.0284x; 1.3722x over previous
//
#include <hip/hip_runtime.h>
#include <hip/hip_bf16.h>
#include <math.h>

// CaptionModel: 200-step GRU (B=256,H=512) + projection V=100.
// Round-8: 512 threads/block (8 waves = 2/SIMD TLP), h-in-register carry,
// chunk-major LDS staging, K-parity wave split. Round-7 showed 16 us/step
// almost entirely exposed latency at 1 wave/SIMD. Two waves per SIMD
// (gate-group g x K-parity) interleave so MFMA-chain / L2-B / L3-staging
// latencies overlap. Numerics: per-chunk zeroed f32 MFMA 6-chains are
// BIT-IDENTICAL to rounds 4-7 (absmax canary 0.0078125); only f64 combine
// order changes (parity halves summed separately): ~2^-50 rel, ~1e-10 after
// the 1.8e5 chaos amplification - negligible.
// Sync protocol unchanged from round-7 (passed): relaxed sc1 agent atomics
// for cross-XCD hsp, no L2 inv/wb in the loop, per-mh-group barrier.

typedef __bf16 bf16_t;
typedef __bf16 bf16x8 __attribute__((ext_vector_type(8)));
typedef float f32x4 __attribute__((ext_vector_type(4)));
typedef unsigned long long u64;
typedef unsigned short u16;

#define B_ 256
#define H_ 512
#define V_ 100
#define T_ 200
#define NF_ 131072              // B_*H_
#define SLAB_ 24576             // per (group,jt): 3 sp * 16 c * 16 r * 32 k
#define MFMA(a,b,c) __builtin_amdgcn_mfma_f32_16x16x32_bf16((a),(b),(c),0,0,0)

__device__ __forceinline__ float ld_in(const void* p, long i, int isf32) {
    return isf32 ? ((const float*)p)[i] : (float)((const bf16_t*)p)[i];
}

__device__ __forceinline__ bf16_t split_pick(double v, int sp) {
    bf16_t a = (bf16_t)(float)v;
    if (sp == 0) return a;
    double r1 = v - (double)(float)a;
    bf16_t b = (bf16_t)(float)r1;
    if (sp == 1) return b;
    double r2 = r1 - (double)(float)b;
    return (bf16_t)(float)r2;
}

union bfbits { __bf16 b; u16 u; };

// ---------------------------------------------------------------------------
// Canonical buffers (chunk-major, MFMA fragment = 16 B/lane):
//  WB [4 grp][32 jt][3 sp][16 c][16 r][32 k]  grps: Rc, Zc, NI, NH
//  W0 [3 grp][32 jt][3 sp][16 c][16 r][32 k]  wh-only (s==0)
//  PB [7 vt][2 sp][16 c][16 r][32 k]
//  BB [4][512] f64; gi0[1536] f64 = x0 @ w_ih^T
__global__ __launch_bounds__(256) void convert_kernel(
    const void* __restrict__ feat, const void* __restrict__ embed,
    const void* __restrict__ wih,  const void* __restrict__ whh,
    const void* __restrict__ bih,  const void* __restrict__ bhh,
    const void* __restrict__ pw,   const void* __restrict__ pb,
    char* __restrict__ barr, int* __restrict__ flag,
    bf16_t* __restrict__ WB, bf16_t* __restrict__ W0, bf16_t* __restrict__ PB,
    bf16_t* __restrict__ hsp, double* __restrict__ hf,
    double* __restrict__ BB, double* __restrict__ pbd, double* __restrict__ gi0)
{
    // runtime dtype detection on feat (~N(0,1)): bf16 buffer -> low u16 of a
    // u32 is a plausible bf16 (~128/128); f32 -> mantissa bits (~15/128).
    __shared__ int s_cnt;
    if (threadIdx.x == 0) s_cnt = 0;
    __syncthreads();
    if (threadIdx.x < 128) {
        unsigned w = ((const unsigned*)feat)[threadIdx.x];
        unsigned e = (w >> 7) & 0xFFu;
        if (e >= 0x68u && e <= 0x85u) atomicAdd(&s_cnt, 1);
    }
    __syncthreads();
    const int isf32 = (s_cnt < 96) ? 1 : 0;
    if (blockIdx.x == 0) {
        if (threadIdx.x == 0) *flag = isf32;
        if (threadIdx.x < 16) {       // zero per-group barrier state
            int g = threadIdx.x & 7;
            int* p = (int*)(barr + ((threadIdx.x < 8) ? (size_t)g * 128
                                                      : 4096 + (size_t)g * 128));
            *p = 0;
        }
    }

    const long S0 = NF_;
    const long S1 = 3145728;      // WB elems
    const long S2 = 2359296;      // W0
    const long S3 = 114688;       // PB
    const long S4 = 2048;         // BB
    const long S5 = 100;          // pbd
    const long S6 = 1536;         // gi0
    const long TOT = S0 + S1 + S2 + S3 + S4 + S5 + S6;

    for (long g = blockIdx.x * 256L + threadIdx.x; g < TOT;
         g += (long)gridDim.x * 256L) {
        long i = g;
        if (i < S0) {
            double v = (double)ld_in(feat, i, isf32);
            hf[i] = v;
            hsp[i] = split_pick(v, 0);
            hsp[NF_ + i] = split_pick(v, 1);
            hsp[2 * NF_ + i] = split_pick(v, 2);
            continue;
        }
        i -= S0;
        if (i < S1) {
            long slab = i / SLAB_;  long rem = i % SLAB_;
            int grp = (int)(slab >> 5), jt = (int)(slab & 31);
            int sp = (int)(rem / 8192); long r2 = rem % 8192;
            int c = (int)(r2 / 512), r = (int)((r2 % 512) / 32), kk = (int)(r2 & 31);
            long n = jt * 16 + r, k = c * 32 + kk;
            double v;
            if (grp == 0)      v = (double)ld_in(wih, n * H_ + k, isf32) +
                                   (double)ld_in(whh, n * H_ + k, isf32);
            else if (grp == 1) v = (double)ld_in(wih, (512 + n) * H_ + k, isf32) +
                                   (double)ld_in(whh, (512 + n) * H_ + k, isf32);
            else if (grp == 2) v = (double)ld_in(wih, (1024 + n) * H_ + k, isf32);
            else               v = (double)ld_in(whh, (1024 + n) * H_ + k, isf32);
            WB[i] = split_pick(v, sp);
            continue;
        }
        i -= S1;
        if (i < S2) {
            long slab = i / SLAB_;  long rem = i % SLAB_;
            int grp = (int)(slab >> 5), jt = (int)(slab & 31);
            int sp = (int)(rem / 8192); long r2 = rem % 8192;
            int c = (int)(r2 / 512), r = (int)((r2 % 512) / 32), kk = (int)(r2 & 31);
            long n = jt * 16 + r, k = c * 32 + kk;
            long row = (grp == 0) ? n : (grp == 1) ? (512 + n) : (1024 + n);
            W0[i] = split_pick((double)ld_in(whh, row * H_ + k, isf32), sp);
            continue;
        }
        i -= S2;
        if (i < S3) {
            int vt = (int)(i / 16384); long rem = i % 16384;
            int sp = (int)(rem / 8192); long r2 = rem % 8192;
            int c = (int)(r2 / 512), r = (int)((r2 % 512) / 32), kk = (int)(r2 & 31);
            int v = vt * 16 + r;
            long k = c * 32 + kk;
            double val = (v < V_) ? (double)ld_in(pw, (long)v * H_ + k, isf32) : 0.0;
            PB[i] = split_pick(val, sp);
            continue;
        }
        i -= S3;
        if (i < S4) {
            int grp = (int)(i / 512), j = (int)(i & 511);
            double v;
            if (grp == 0)      v = (double)ld_in(bih, j, isf32) + (double)ld_in(bhh, j, isf32);
            else if (grp == 1) v = (double)ld_in(bih, 512 + j, isf32) + (double)ld_in(bhh, 512 + j, isf32);
            else if (grp == 2) v = (double)ld_in(bih, 1024 + j, isf32);
            else               v = (double)ld_in(bhh, 1024 + j, isf32);
            BB[i] = v;
            continue;
        }
        i -= S4;
        if (i < S5) { pbd[i] = (double)ld_in(pb, i, isf32); continue; }
        i -= S5;
        if (i < S6) {
            double acc = 0.0;
            for (int k = 0; k < H_; ++k)
                acc += (double)ld_in(embed, k, isf32) *
                       (double)ld_in(wih, i * H_ + k, isf32);
            gi0[i] = acc;
        }
    }
}

// ---------------------------------------------------------------------------
// Persistent: 256 blocks x 512 threads (8 waves = 2/SIMD).
// XCD swizzle: x=b&7, l=b>>3; jt=(x&3)*8+(l&7), mh=(x>>2)*4+(l>>3).
// Wave w: gate-group g=w&3, K-parity par=w>>2 (chunks c with (c&1)==par).
// SIMD w%4=g hosts both parities of group g -> TLP hides chain latency.
// Staging: 4 quarters of [dump 6 u64/thread -> LDS chunk-major; compute].
__global__ __launch_bounds__(512) void gru_persist(
    const bf16_t* __restrict__ WB, const bf16_t* __restrict__ W0,
    const bf16_t* __restrict__ PB,
    bf16_t* __restrict__ hsp,      // [2 pp][3 sp][NF_] - cross-XCD, sc1 only
    const double* __restrict__ hf, // initial h (f64) - read once
    const double* __restrict__ BB, const double* __restrict__ pbd,
    const double* __restrict__ gi0,
    const int* __restrict__ flag, char* __restrict__ barr,
    void* __restrict__ outp)
{
    __shared__ __align__(16) __bf16 Ast[3][4][32][32];   // 24.5 KB chunk-major
    __shared__ double Gm[8][32][16];                     // 32 KB

    const int tid = threadIdx.x;
    const int w = tid >> 6;
    const int g = w & 3;             // gate group (Rc,Zc,NI,NH)
    const int par = w >> 2;          // K-chunk parity
    const int lane = tid & 63;
    const int ln = lane & 15;
    const int quad = lane >> 4;
    const int b = blockIdx.x;
    const int x = b & 7;             // assumed XCD (round-robin)
    const int l = b >> 3;
    const int jt = (x & 3) * 8 + (l & 7);
    const int mh = (x >> 2) * 4 + (l >> 3);
    const int m0base = mh * 32;
    const int isf32 = *flag;

    int* myc = (int*)(barr + (size_t)mh * 128);
    int* mys = (int*)(barr + 4096 + (size_t)mh * 128);

    // h element owned by this thread, carried in register (f64) all 200 steps
    const int gm = tid >> 4;         // 0..31 (m row within block)
    const int gj = tid & 15;         // 0..15 (j col within tile)
    double hreg = hf[(long)(m0base + gm) * H_ + jt * 16 + gj];
    // step-invariant bias hoist
    const int jg = jt * 16 + gj;
    const double bbR = BB[jg], bbZ = BB[512 + jg];
    const double bbNI = BB[1024 + jg], bbNH = BB[1536 + jg];
    const double g0R = gi0[jg], g0Z = gi0[512 + jg], g0NI = gi0[1024 + jg];

    for (int s = 0; s <= T_; ++s) {
        const u64* hin64 = (const u64*)(hsp + (long)(s & 1) * 3 * NF_);

        // per-wave GEMM setup
        const bf16_t* wp = nullptr;
        bool gemm = false;
        if (s < T_) {
            bool skip = false;
            const bf16_t* wslab;
            if (s == 0) {
                skip = (g == 2);                       // NI at s=0 from gi0
                int gg = (g == 3) ? 2 : g;
                wslab = W0 + (long)(gg * 32 + jt) * SLAB_;
            } else {
                wslab = WB + (long)(g * 32 + jt) * SLAB_;
            }
            wp = wslab + ln * 32 + quad * 8;
            gemm = !skip;
        }
        const bool doproj = (s >= 1 && jt < 14 && w == (s & 7));
        const int tpj = jt & 1;
        const bf16_t* pbB1 = PB + (long)(jt >> 1) * 16384 + ln * 32 + quad * 8;
        const bf16_t* pbB2 = pbB1 + 8192;

        double dg0[4] = {0, 0, 0, 0}, dg1[4] = {0, 0, 0, 0};
        f32x4 pacc = {0.f, 0.f, 0.f, 0.f};
        bf16x8 Bc[3], Bn[3];
        if (gemm) {
            #pragma unroll
            for (int sp = 0; sp < 3; ++sp)             // first chunk = par
                Bc[sp] = *(const bf16x8*)(wp + sp * 8192 + par * 512);
        }

        // prefetch staging quarter 0 (relaxed agent sc1: coherent, no L2 inv)
        u64 sreg[6];
        #pragma unroll
        for (int i = 0; i < 6; ++i) {
            int u = i * 512 + tid;
            int sp = u >> 10, row = (u >> 5) & 31, k64 = u & 31;
            long off = (long)sp * 32768 + (long)(m0base + row) * 128 + k64;
            sreg[i] = __hip_atomic_load(hin64 + off, __ATOMIC_RELAXED,
                                        __HIP_MEMORY_SCOPE_AGENT);
        }

        for (int q = 0; q < 4; ++q) {
            // dump quarter q -> LDS (chunk-major: [sp][lc][row][kk])
            #pragma unroll
            for (int i = 0; i < 6; ++i) {
                int u = i * 512 + tid;
                int sp = u >> 10, row = (u >> 5) & 31, k64 = u & 31;
                *(u64*)&Ast[sp][k64 >> 3][row][(k64 & 7) * 4] = sreg[i];
            }
            if (q < 3) {
                #pragma unroll
                for (int i = 0; i < 6; ++i) {
                    int u = i * 512 + tid;
                    int sp = u >> 10, row = (u >> 5) & 31, k64 = u & 31;
                    long off = (long)sp * 32768 + (long)(m0base + row) * 128 +
                               (q + 1) * 32 + k64;
                    sreg[i] = __hip_atomic_load(hin64 + off, __ATOMIC_RELAXED,
                                                __HIP_MEMORY_SCOPE_AGENT);
                }
            }
            __syncthreads();

            if (gemm) {
                #pragma unroll
                for (int t = 0; t < 2; ++t) {
                    const int lc = 2 * t + par;        // local chunk (parity)
                    const int c = q * 4 + lc;          // global chunk
                    if (c < 14 + par) {                // prefetch next parity chunk
                        const int cn = c + 2;
                        const int qn = cn >> 2;
                        if (qn == q || t == 1) {       // next is in this or next quarter
                            #pragma unroll
                            for (int sp = 0; sp < 3; ++sp)
                                Bn[sp] = *(const bf16x8*)(wp + sp * 8192 + cn * 512);
                        }
                    }
                    bf16x8 A0[3], A1[3];
                    #pragma unroll
                    for (int sp = 0; sp < 3; ++sp) {
                        A0[sp] = *(const bf16x8*)&Ast[sp][lc][ln][quad * 8];
                        A1[sp] = *(const bf16x8*)&Ast[sp][lc][16 + ln][quad * 8];
                    }
                    f32x4 t0 = {0.f, 0.f, 0.f, 0.f};
                    t0 = MFMA(A0[0], Bc[2], t0);
                    t0 = MFMA(A0[1], Bc[1], t0);
                    t0 = MFMA(A0[2], Bc[0], t0);
                    t0 = MFMA(A0[0], Bc[1], t0);
                    t0 = MFMA(A0[1], Bc[0], t0);
                    t0 = MFMA(A0[0], Bc[0], t0);
                    f32x4 t1 = {0.f, 0.f, 0.f, 0.f};
                    t1 = MFMA(A1[0], Bc[2], t1);
                    t1 = MFMA(A1[1], Bc[1], t1);
                    t1 = MFMA(A1[2], Bc[0], t1);
                    t1 = MFMA(A1[0], Bc[1], t1);
                    t1 = MFMA(A1[1], Bc[0], t1);
                    t1 = MFMA(A1[0], Bc[0], t1);
                    #pragma unroll
                    for (int i = 0; i < 4; ++i) {
                        dg0[i] += (double)t0[i];
                        dg1[i] += (double)t1[i];
                    }
                    if (c < 14 + par) {
                        #pragma unroll
                        for (int sp = 0; sp < 3; ++sp) Bc[sp] = Bn[sp];
                    }
                }
            }
            if (doproj) {
                #pragma unroll
                for (int lc = 0; lc < 4; ++lc) {       // ascending c: bit-exact
                    const int c = q * 4 + lc;
                    bf16x8 pa1 = *(const bf16x8*)&Ast[0][lc][tpj * 16 + ln][quad * 8];
                    bf16x8 pa2 = *(const bf16x8*)&Ast[1][lc][tpj * 16 + ln][quad * 8];
                    bf16x8 b1v = *(const bf16x8*)(pbB1 + c * 512);
                    bf16x8 b2v = *(const bf16x8*)(pbB2 + c * 512);
                    pacc = MFMA(pa1, b2v, pacc);
                    pacc = MFMA(pa2, b1v, pacc);
                    pacc = MFMA(pa1, b1v, pacc);
                }
            }
            __syncthreads();     // protect Ast before next quarter's dump
        }

        // projection output: h_s @ pw^T + pb -> out column s-1
        if (doproj) {
            const int v = (jt >> 1) * 16 + ln;
            if (v < V_) {
                const double pbv = pbd[v];
                const int mtp = mh * 2 + tpj;
                #pragma unroll
                for (int i = 0; i < 4; ++i) {
                    const int m = mtp * 16 + quad * 4 + i;
                    const long idx = ((long)m * V_ + v) * T_ + (s - 1);
                    const float val = (float)((double)pacc[i] + pbv);
                    if (isf32) ((float*)outp)[idx] = val;
                    else       ((bf16_t*)outp)[idx] = (bf16_t)val;
                }
            }
        }

        if (s < T_) {
            #pragma unroll
            for (int i = 0; i < 4; ++i) {
                Gm[w][quad * 4 + i][ln] = dg0[i];
                Gm[w][16 + quad * 4 + i][ln] = dg1[i];
            }
            __syncthreads();

            // gate: one output per thread, all f64; h carried in hreg
            {
                double R  = Gm[0][gm][gj] + Gm[4][gm][gj] + bbR;
                double Z  = Gm[1][gm][gj] + Gm[5][gm][gj] + bbZ;
                double NI = Gm[2][gm][gj] + Gm[6][gm][gj] + bbNI;
                double NH = Gm[3][gm][gj] + Gm[7][gm][gj] + bbNH;
                if (s == 0) { R += g0R; Z += g0Z; NI += g0NI; }
                const double r = 1.0 / (1.0 + exp(-R));
                const double z = 1.0 / (1.0 + exp(-Z));
                const double pre = NI + r * NH;
                const double n = 1.0 - 2.0 / (exp(2.0 * pre) + 1.0);   // tanh
                hreg = (1.0 - z) * n + z * hreg;
                const long oi = (long)(m0base + gm) * H_ + jg;
                u16* ho = (u16*)(hsp + (long)((s + 1) & 1) * 3 * NF_);
                bfbits q1, q2, q3;
                q1.b = (bf16_t)(float)hreg;  double r1 = hreg - (double)(float)q1.b;
                q2.b = (bf16_t)(float)r1;    double r2 = r1 - (double)(float)q2.b;
                q3.b = (bf16_t)(float)r2;
                __hip_atomic_store(ho + oi, q1.u, __ATOMIC_RELAXED, __HIP_MEMORY_SCOPE_AGENT);
                __hip_atomic_store(ho + NF_ + oi, q2.u, __ATOMIC_RELAXED, __HIP_MEMORY_SCOPE_AGENT);
                __hip_atomic_store(ho + 2 * NF_ + oi, q3.u, __ATOMIC_RELAXED, __HIP_MEMORY_SCOPE_AGENT);
            }

            // per-mh barrier (32 blocks): syncthreads drains each wave's
            // vmcnt (hsp sc1 stores visible), then relaxed arrival + all-
            // thread sense poll (no cache maintenance anywhere).
            __syncthreads();
            if (tid == 0) {
                int old = __hip_atomic_fetch_add(myc, 1, __ATOMIC_RELAXED,
                                                 __HIP_MEMORY_SCOPE_AGENT);
                if (old == 32 * (s + 1) - 1)
                    __hip_atomic_store(mys, s + 1, __ATOMIC_RELAXED,
                                       __HIP_MEMORY_SCOPE_AGENT);
            }
            int lim = 0;
            while (__hip_atomic_load(mys, __ATOMIC_RELAXED,
                                     __HIP_MEMORY_SCOPE_AGENT) < s + 1) {
                __builtin_amdgcn_s_sleep(2);
                if (++lim > 100000000) break;          // failsafe: no hang
            }
        }
    }
}

// ---------------------------------------------------------------------------
extern "C" void kernel_launch(void* const* d_in, const int* in_sizes, int n_in,
                              void* d_out, int out_size, void* d_ws, size_t ws_size,
                              hipStream_t stream) {
    char* ws = (char*)d_ws;
    char*   barr = ws;                          // [0,8192): cnt/sense lines
    int*    flag = (int*)(ws + 8192);
    bf16_t* WB  = (bf16_t*)(ws + 8448);         // 6,291,456 B
    bf16_t* W0  = (bf16_t*)(ws + 6299904);      // 4,718,592 B
    bf16_t* PB  = (bf16_t*)(ws + 11018496);     //   458,752 B
    bf16_t* hsp = (bf16_t*)(ws + 11477248);     // 1,572,864 B
    double* hf  = (double*)(ws + 13050112);     // 1,048,576 B (initial h)
    double* BB  = (double*)(ws + 15147264);     //    16,384 B
    double* pbd = (double*)(ws + 15163648);     //     1,024 B
    double* gi0 = (double*)(ws + 15164672);     //    12,288 B  (end ~14.5 MB)

    convert_kernel<<<1024, 256, 0, stream>>>(
        d_in[0], d_in[1], d_in[2], d_in[3], d_in[4], d_in[5], d_in[6], d_in[7],
        barr, flag, WB, W0, PB, hsp, hf, BB, pbd, gi0);

    gru_persist<<<256, 512, 0, stream>>>(
        WB, W0, PB, hsp, hf, BB, pbd, gi0, flag, barr, d_out);
}

// Round 10
// 2244.177 us; speedup vs baseline: 5.3739x; 1.0687x over previous
//
#include <hip/hip_runtime.h>
#include <hip/hip_bf16.h>
#include <math.h>

// CaptionModel: 200-step GRU (B=256,H=512) + projection V=100.
// Round-10 (bisection): round-8 base (passed, 2398us) + three data-identical
// changes only: (1) LDS fragment-linear layout w/ ln^quad XOR swizzle ->
// conflict-free MFMA A-reads (round-8 counter: 1.2e8 conflict cycles);
// (2) B fragments hoisted to registers (Breg[8][3]) - W0 preloaded, swapped
// to WB after s==0; (3) 2-deep staging prefetch. Global hsp layout, convert
// kernel, gate stores, and fetch_add+sense barrier are round-8 VERBATIM.
// Round-9's global-layout permute + flag-array barrier (absmax 0.0859) are
// abandoned. Canary: absmax must be exactly 0.0078125.

typedef __bf16 bf16_t;
typedef __bf16 bf16x8 __attribute__((ext_vector_type(8)));
typedef float f32x4 __attribute__((ext_vector_type(4)));
typedef unsigned long long u64;
typedef unsigned short u16;

#define B_ 256
#define H_ 512
#define V_ 100
#define T_ 200
#define NF_ 131072              // B_*H_
#define SLAB_ 24576             // per (group,jt): 3 sp * 16 c * 16 r * 32 k
#define MFMA(a,b,c) __builtin_amdgcn_mfma_f32_16x16x32_bf16((a),(b),(c),0,0,0)

__device__ __forceinline__ float ld_in(const void* p, long i, int isf32) {
    return isf32 ? ((const float*)p)[i] : (float)((const bf16_t*)p)[i];
}

__device__ __forceinline__ bf16_t split_pick(double v, int sp) {
    bf16_t a = (bf16_t)(float)v;
    if (sp == 0) return a;
    double r1 = v - (double)(float)a;
    bf16_t b = (bf16_t)(float)r1;
    if (sp == 1) return b;
    double r2 = r1 - (double)(float)b;
    return (bf16_t)(float)r2;
}

union bfbits { __bf16 b; u16 u; };

// ---------------------------------------------------------------------------
// Canonical buffers (round-8 verbatim):
//  WB [4 grp][32 jt][3 sp][16 c][16 r][32 k]  grps: Rc, Zc, NI, NH
//  W0 [3 grp][32 jt][3 sp][16 c][16 r][32 k]  wh-only (s==0)
//  PB [7 vt][2 sp][16 c][16 r][32 k]
//  hsp linear [2 pp][3 sp][m 256][col 512];  BB [4][512] f64; gi0[1536] f64
__global__ __launch_bounds__(256) void convert_kernel(
    const void* __restrict__ feat, const void* __restrict__ embed,
    const void* __restrict__ wih,  const void* __restrict__ whh,
    const void* __restrict__ bih,  const void* __restrict__ bhh,
    const void* __restrict__ pw,   const void* __restrict__ pb,
    char* __restrict__ barr, int* __restrict__ flag,
    bf16_t* __restrict__ WB, bf16_t* __restrict__ W0, bf16_t* __restrict__ PB,
    bf16_t* __restrict__ hsp, double* __restrict__ hf,
    double* __restrict__ BB, double* __restrict__ pbd, double* __restrict__ gi0)
{
    // runtime dtype detection on feat (~N(0,1)): bf16 buffer -> low u16 of a
    // u32 is a plausible bf16 (~128/128); f32 -> mantissa bits (~15/128).
    __shared__ int s_cnt;
    if (threadIdx.x == 0) s_cnt = 0;
    __syncthreads();
    if (threadIdx.x < 128) {
        unsigned w = ((const unsigned*)feat)[threadIdx.x];
        unsigned e = (w >> 7) & 0xFFu;
        if (e >= 0x68u && e <= 0x85u) atomicAdd(&s_cnt, 1);
    }
    __syncthreads();
    const int isf32 = (s_cnt < 96) ? 1 : 0;
    if (blockIdx.x == 0) {
        if (threadIdx.x == 0) *flag = isf32;
        if (threadIdx.x < 16) {       // zero per-group barrier state
            int g = threadIdx.x & 7;
            int* p = (int*)(barr + ((threadIdx.x < 8) ? (size_t)g * 128
                                                      : 4096 + (size_t)g * 128));
            *p = 0;
        }
    }

    const long S0 = NF_;
    const long S1 = 3145728;      // WB elems
    const long S2 = 2359296;      // W0
    const long S3 = 114688;       // PB
    const long S4 = 2048;         // BB
    const long S5 = 100;          // pbd
    const long S6 = 1536;         // gi0
    const long TOT = S0 + S1 + S2 + S3 + S4 + S5 + S6;

    for (long g = blockIdx.x * 256L + threadIdx.x; g < TOT;
         g += (long)gridDim.x * 256L) {
        long i = g;
        if (i < S0) {
            double v = (double)ld_in(feat, i, isf32);
            hf[i] = v;
            hsp[i] = split_pick(v, 0);
            hsp[NF_ + i] = split_pick(v, 1);
            hsp[2 * NF_ + i] = split_pick(v, 2);
            continue;
        }
        i -= S0;
        if (i < S1) {
            long slab = i / SLAB_;  long rem = i % SLAB_;
            int grp = (int)(slab >> 5), jt = (int)(slab & 31);
            int sp = (int)(rem / 8192); long r2 = rem % 8192;
            int c = (int)(r2 / 512), r = (int)((r2 % 512) / 32), kk = (int)(r2 & 31);
            long n = jt * 16 + r, k = c * 32 + kk;
            double v;
            if (grp == 0)      v = (double)ld_in(wih, n * H_ + k, isf32) +
                                   (double)ld_in(whh, n * H_ + k, isf32);
            else if (grp == 1) v = (double)ld_in(wih, (512 + n) * H_ + k, isf32) +
                                   (double)ld_in(whh, (512 + n) * H_ + k, isf32);
            else if (grp == 2) v = (double)ld_in(wih, (1024 + n) * H_ + k, isf32);
            else               v = (double)ld_in(whh, (1024 + n) * H_ + k, isf32);
            WB[i] = split_pick(v, sp);
            continue;
        }
        i -= S1;
        if (i < S2) {
            long slab = i / SLAB_;  long rem = i % SLAB_;
            int grp = (int)(slab >> 5), jt = (int)(slab & 31);
            int sp = (int)(rem / 8192); long r2 = rem % 8192;
            int c = (int)(r2 / 512), r = (int)((r2 % 512) / 32), kk = (int)(r2 & 31);
            long n = jt * 16 + r, k = c * 32 + kk;
            long row = (grp == 0) ? n : (grp == 1) ? (512 + n) : (1024 + n);
            W0[i] = split_pick((double)ld_in(whh, row * H_ + k, isf32), sp);
            continue;
        }
        i -= S2;
        if (i < S3) {
            int vt = (int)(i / 16384); long rem = i % 16384;
            int sp = (int)(rem / 8192); long r2 = rem % 8192;
            int c = (int)(r2 / 512), r = (int)((r2 % 512) / 32), kk = (int)(r2 & 31);
            int v = vt * 16 + r;
            long k = c * 32 + kk;
            double val = (v < V_) ? (double)ld_in(pw, (long)v * H_ + k, isf32) : 0.0;
            PB[i] = split_pick(val, sp);
            continue;
        }
        i -= S3;
        if (i < S4) {
            int grp = (int)(i / 512), j = (int)(i & 511);
            double v;
            if (grp == 0)      v = (double)ld_in(bih, j, isf32) + (double)ld_in(bhh, j, isf32);
            else if (grp == 1) v = (double)ld_in(bih, 512 + j, isf32) + (double)ld_in(bhh, 512 + j, isf32);
            else if (grp == 2) v = (double)ld_in(bih, 1024 + j, isf32);
            else               v = (double)ld_in(bhh, 1024 + j, isf32);
            BB[i] = v;
            continue;
        }
        i -= S4;
        if (i < S5) { pbd[i] = (double)ld_in(pb, i, isf32); continue; }
        i -= S5;
        if (i < S6) {
            double acc = 0.0;
            for (int k = 0; k < H_; ++k)
                acc += (double)ld_in(embed, k, isf32) *
                       (double)ld_in(wih, i * H_ + k, isf32);
            gi0[i] = acc;
        }
    }
}

// ---------------------------------------------------------------------------
// Persistent: 256 blocks x 512 threads (8 waves = 2/SIMD).
// XCD swizzle: x=b&7, l=b>>3; jt=(x&3)*8+(l&7), mh=(x>>2)*4+(l>>3).
// Wave w: gate group g=w&3, K-parity par=w>>2. Breg[n][sp] = this wave's 8
// weight chunks in registers (W0 for s==0; swapped to WB after step 0).
// LDS staging is fragment-linear with ln^quad swizzle:
//   u64 pos = sp*1024 + lc*256 + tile*128 + (((row&15)^qd)|(qd<<4))*2 + half
// so per-quarter-wave MFMA A-reads are dense 16B/lane (conflict-free).
__global__ __launch_bounds__(512, 2) void gru_persist(
    const bf16_t* __restrict__ WB, const bf16_t* __restrict__ W0,
    const bf16_t* __restrict__ PB,
    bf16_t* __restrict__ hsp,      // [2 pp][3 sp][NF_] linear, sc1 only
    const double* __restrict__ hf, // initial h (f64)
    const double* __restrict__ BB, const double* __restrict__ pbd,
    const double* __restrict__ gi0,
    const int* __restrict__ flag, char* __restrict__ barr,
    void* __restrict__ outp)
{
    __shared__ __align__(16) u64 Ast64[3072];     // 24.5 KB, one quarter
    __shared__ double Gm[8][32][16];              // 32 KB

    const int tid = threadIdx.x;
    const int w = tid >> 6;
    const int g = w & 3;
    const int par = w >> 2;
    const int lane = tid & 63;
    const int ln = lane & 15;
    const int quad = lane >> 4;
    const int b = blockIdx.x;
    const int x = b & 7;             // assumed XCD (round-robin)
    const int l = b >> 3;
    const int jt = (x & 3) * 8 + (l & 7);
    const int mh = (x >> 2) * 4 + (l >> 3);
    const int m0base = mh * 32;
    const int isf32 = *flag;
    const __bf16* Abase = (const __bf16*)Ast64;

    int* myc = (int*)(barr + (size_t)mh * 128);
    int* mys = (int*)(barr + 4096 + (size_t)mh * 128);

    // gate-phase ownership + step-invariant hoists (round-8 verbatim)
    const int gm = tid >> 4;
    const int gj = tid & 15;
    const int jg = jt * 16 + gj;
    double hreg = hf[(long)(m0base + gm) * H_ + jg];
    const double bbR = BB[jg], bbZ = BB[512 + jg];
    const double bbNI = BB[1024 + jg], bbNH = BB[1536 + jg];
    const double g0R = gi0[jg], g0Z = gi0[512 + jg], g0NI = gi0[1024 + jg];

    // weight fragments in registers: Breg[n][sp], chunk c = par + 2n
    bf16x8 Breg[8][3];
    {
        const int gg = (g == 3) ? 2 : g;          // s==0 slab (g==2 unused)
        const bf16_t* wpre = W0 + (long)(gg * 32 + jt) * SLAB_ + ln * 32 + quad * 8;
        #pragma unroll
        for (int n = 0; n < 8; ++n)
            #pragma unroll
            for (int sp = 0; sp < 3; ++sp)
                Breg[n][sp] = *(const bf16x8*)(wpre + sp * 8192 + (par + 2 * n) * 512);
    }
    const bf16_t* wpW = WB + (long)(g * 32 + jt) * SLAB_ + ln * 32 + quad * 8;

    const int tpj = jt & 1;
    const bf16_t* pbB1 = PB + (long)(jt >> 1) * 16384 + ln * 32 + quad * 8;
    const bf16_t* pbB2 = pbB1 + 8192;
    // swizzled element offset for this lane's A-fragment reads
    const int lf = ((ln ^ quad) | (quad << 4)) * 8;

    for (int s = 0; s <= T_; ++s) {
        const u64* hin64 = (const u64*)(hsp + (long)(s & 1) * 3 * NF_);
        const bool gemm = (s < T_) && !(s == 0 && g == 2);
        const bool doproj = (s >= 1 && jt < 14 && w == (s & 7));

        double dg0[4] = {0, 0, 0, 0}, dg1[4] = {0, 0, 0, 0};
        f32x4 pacc = {0.f, 0.f, 0.f, 0.f};

        // 2-deep staging prefetch: quarters 0 and 1 (round-8 addressing)
        u64 sreg[12];
        #pragma unroll
        for (int qq = 0; qq < 2; ++qq)
            #pragma unroll
            for (int i = 0; i < 6; ++i) {
                int u = i * 512 + tid;
                int sp = u >> 10, row = (u >> 5) & 31, k64 = u & 31;
                long off = (long)sp * 32768 + (long)(m0base + row) * 128 +
                           qq * 32 + k64;
                sreg[qq * 6 + i] = __hip_atomic_load(hin64 + off, __ATOMIC_RELAXED,
                                                     __HIP_MEMORY_SCOPE_AGENT);
            }

        #pragma unroll
        for (int q = 0; q < 4; ++q) {
            const int slot = (q & 1) * 6;
            // dump quarter q -> LDS (fragment-linear + ln^qd swizzle)
            #pragma unroll
            for (int i = 0; i < 6; ++i) {
                int u = i * 512 + tid;
                int sp = u >> 10, row = (u >> 5) & 31, k64 = u & 31;
                int lc = k64 >> 3, qd = (k64 & 7) >> 1, half = k64 & 1;
                int lpos = ((row & 15) ^ qd) | (qd << 4);
                Ast64[sp * 1024 + lc * 256 + (row >> 4) * 128 + lpos * 2 + half] =
                    sreg[slot + i];
            }
            __syncthreads();
            if (q < 2) {     // issue quarter q+2
                #pragma unroll
                for (int i = 0; i < 6; ++i) {
                    int u = i * 512 + tid;
                    int sp = u >> 10, row = (u >> 5) & 31, k64 = u & 31;
                    long off = (long)sp * 32768 + (long)(m0base + row) * 128 +
                               (q + 2) * 32 + k64;
                    sreg[slot + i] = __hip_atomic_load(hin64 + off, __ATOMIC_RELAXED,
                                                       __HIP_MEMORY_SCOPE_AGENT);
                }
            }

            if (gemm) {
                #pragma unroll
                for (int t = 0; t < 2; ++t) {
                    const int lc = 2 * t + par;
                    const int n = 2 * q + t;
                    bf16x8 A0[3], A1[3];
                    #pragma unroll
                    for (int sp = 0; sp < 3; ++sp) {
                        A0[sp] = *(const bf16x8*)(Abase + sp * 4096 + lc * 1024 + lf);
                        A1[sp] = *(const bf16x8*)(Abase + sp * 4096 + lc * 1024 + 512 + lf);
                    }
                    f32x4 t0 = {0.f, 0.f, 0.f, 0.f};
                    t0 = MFMA(A0[0], Breg[n][2], t0);
                    t0 = MFMA(A0[1], Breg[n][1], t0);
                    t0 = MFMA(A0[2], Breg[n][0], t0);
                    t0 = MFMA(A0[0], Breg[n][1], t0);
                    t0 = MFMA(A0[1], Breg[n][0], t0);
                    t0 = MFMA(A0[0], Breg[n][0], t0);
                    f32x4 t1 = {0.f, 0.f, 0.f, 0.f};
                    t1 = MFMA(A1[0], Breg[n][2], t1);
                    t1 = MFMA(A1[1], Breg[n][1], t1);
                    t1 = MFMA(A1[2], Breg[n][0], t1);
                    t1 = MFMA(A1[0], Breg[n][1], t1);
                    t1 = MFMA(A1[1], Breg[n][0], t1);
                    t1 = MFMA(A1[0], Breg[n][0], t1);
                    #pragma unroll
                    for (int i = 0; i < 4; ++i) {
                        dg0[i] += (double)t0[i];
                        dg1[i] += (double)t1[i];
                    }
                }
            }
            if (doproj) {
                #pragma unroll
                for (int lc = 0; lc < 4; ++lc) {   // ascending c: bit-exact
                    const int c = q * 4 + lc;
                    bf16x8 pa1 = *(const bf16x8*)(Abase + 0 * 4096 + lc * 1024 + tpj * 512 + lf);
                    bf16x8 pa2 = *(const bf16x8*)(Abase + 1 * 4096 + lc * 1024 + tpj * 512 + lf);
                    bf16x8 b1v = *(const bf16x8*)(pbB1 + c * 512);
                    bf16x8 b2v = *(const bf16x8*)(pbB2 + c * 512);
                    pacc = MFMA(pa1, b2v, pacc);
                    pacc = MFMA(pa2, b1v, pacc);
                    pacc = MFMA(pa1, b1v, pacc);
                }
            }
            __syncthreads();
        }

        // projection output: h_s @ pw^T + pb -> out column s-1
        if (doproj) {
            const int v = (jt >> 1) * 16 + ln;
            if (v < V_) {
                const double pbv = pbd[v];
                const int mtp = mh * 2 + tpj;
                #pragma unroll
                for (int i = 0; i < 4; ++i) {
                    const int m = mtp * 16 + quad * 4 + i;
                    const long idx = ((long)m * V_ + v) * T_ + (s - 1);
                    const float val = (float)((double)pacc[i] + pbv);
                    if (isf32) ((float*)outp)[idx] = val;
                    else       ((bf16_t*)outp)[idx] = (bf16_t)val;
                }
            }
        }

        if (s < T_) {
            #pragma unroll
            for (int i = 0; i < 4; ++i) {
                Gm[w][quad * 4 + i][ln] = dg0[i];
                Gm[w][16 + quad * 4 + i][ln] = dg1[i];
            }
            __syncthreads();

            // gate: one output per thread, all f64 (round-8 verbatim)
            {
                double R  = Gm[0][gm][gj] + Gm[4][gm][gj] + bbR;
                double Z  = Gm[1][gm][gj] + Gm[5][gm][gj] + bbZ;
                double NI = Gm[2][gm][gj] + Gm[6][gm][gj] + bbNI;
                double NH = Gm[3][gm][gj] + Gm[7][gm][gj] + bbNH;
                if (s == 0) { R += g0R; Z += g0Z; NI += g0NI; }
                const double r = 1.0 / (1.0 + exp(-R));
                const double z = 1.0 / (1.0 + exp(-Z));
                const double pre = NI + r * NH;
                const double n = 1.0 - 2.0 / (exp(2.0 * pre) + 1.0);   // tanh
                hreg = (1.0 - z) * n + z * hreg;
                const long oi = (long)(m0base + gm) * H_ + jg;
                u16* ho = (u16*)(hsp + (long)((s + 1) & 1) * 3 * NF_);
                bfbits q1, q2, q3;
                q1.b = (bf16_t)(float)hreg;  double r1 = hreg - (double)(float)q1.b;
                q2.b = (bf16_t)(float)r1;    double r2 = r1 - (double)(float)q2.b;
                q3.b = (bf16_t)(float)r2;
                __hip_atomic_store(ho + oi, q1.u, __ATOMIC_RELAXED, __HIP_MEMORY_SCOPE_AGENT);
                __hip_atomic_store(ho + NF_ + oi, q2.u, __ATOMIC_RELAXED, __HIP_MEMORY_SCOPE_AGENT);
                __hip_atomic_store(ho + 2 * NF_ + oi, q3.u, __ATOMIC_RELAXED, __HIP_MEMORY_SCOPE_AGENT);
            }

            // per-mh barrier: round-8 verbatim (fetch_add + sense poll)
            __syncthreads();
            if (tid == 0) {
                int old = __hip_atomic_fetch_add(myc, 1, __ATOMIC_RELAXED,
                                                 __HIP_MEMORY_SCOPE_AGENT);
                if (old == 32 * (s + 1) - 1)
                    __hip_atomic_store(mys, s + 1, __ATOMIC_RELAXED,
                                       __HIP_MEMORY_SCOPE_AGENT);
            }
            int lim = 0;
            while (__hip_atomic_load(mys, __ATOMIC_RELAXED,
                                     __HIP_MEMORY_SCOPE_AGENT) < s + 1) {
                __builtin_amdgcn_s_sleep(2);
                if (++lim > 100000000) break;          // failsafe: no hang
            }
            if (s == 0) {   // swap to combined weights for s>=1
                #pragma unroll
                for (int n = 0; n < 8; ++n)
                    #pragma unroll
                    for (int sp = 0; sp < 3; ++sp)
                        Breg[n][sp] = *(const bf16x8*)(wpW + sp * 8192 + (par + 2 * n) * 512);
            }
        }
    }
}

// ---------------------------------------------------------------------------
extern "C" void kernel_launch(void* const* d_in, const int* in_sizes, int n_in,
                              void* d_out, int out_size, void* d_ws, size_t ws_size,
                              hipStream_t stream) {
    char* ws = (char*)d_ws;
    char*   barr = ws;                          // [0,8192): cnt/sense lines
    int*    flag = (int*)(ws + 8192);
    bf16_t* WB  = (bf16_t*)(ws + 8448);         // 6,291,456 B
    bf16_t* W0  = (bf16_t*)(ws + 6299904);      // 4,718,592 B
    bf16_t* PB  = (bf16_t*)(ws + 11018496);     //   458,752 B
    bf16_t* hsp = (bf16_t*)(ws + 11477248);     // 1,572,864 B (2 pp, linear)
    double* hf  = (double*)(ws + 13050112);     // 1,048,576 B (initial h)
    double* BB  = (double*)(ws + 15147264);     //    16,384 B
    double* pbd = (double*)(ws + 15163648);     //     1,024 B
    double* gi0 = (double*)(ws + 15164672);     //    12,288 B  (end ~14.5 MB)

    convert_kernel<<<1024, 256, 0, stream>>>(
        d_in[0], d_in[1], d_in[2], d_in[3], d_in[4], d_in[5], d_in[6], d_in[7],
        barr, flag, WB, W0, PB, hsp, hf, BB, pbd, gi0);

    gru_persist<<<256, 512, 0, stream>>>(
        WB, W0, PB, hsp, hf, BB, pbd, gi0, flag, barr, d_out);
}